// Round 6
// baseline (753.761 us; speedup 1.0000x reference)
//
#include <hip/hip_runtime.h>
#include <hip/hip_bf16.h>
#include <math.h>
#include <float.h>

#define NUM_B 2
#define SEQ_T 2048
#define DIM_D 1024
#define NH 16
#define DH 64
#define KDIM 1024
#define KSEL 8

// attention candidate scheme
#define CAP 32
#define MFMA_MARGIN 0.06f

typedef __attribute__((ext_vector_type(8))) short bf16x8v;   // 8 bf16 (4 VGPR)
typedef __attribute__((ext_vector_type(4))) float f32x4v;    // MFMA acc
typedef __attribute__((ext_vector_type(4))) double f64x4v;   // f64 MFMA acc

__device__ __forceinline__ float bf2f(unsigned int u) {
  union { unsigned int i; float f; } v; v.i = u << 16; return v.f;
}

__device__ __forceinline__ short f2bs(float f) {
  __hip_bfloat16 h = __float2bfloat16(f);
  return *(short*)&h;
}

// split x into hi+lo bf16 (residual ~1.6e-5 rel); store 8 to LDS as 16B each
__device__ __forceinline__ void split8(float4 x0, float4 x1,
                                       unsigned short* __restrict__ hp,
                                       unsigned short* __restrict__ lp) {
  unsigned short h[8], l[8];
  const float xs[8] = {x0.x, x0.y, x0.z, x0.w, x1.x, x1.y, x1.z, x1.w};
#pragma unroll
  for (int j = 0; j < 8; ++j) {
    const short hb = f2bs(xs[j]);
    h[j] = (unsigned short)hb;
    const float hf = bf2f((unsigned int)(unsigned short)hb);
    l[j] = (unsigned short)f2bs(xs[j] - hf);
  }
  *(uint4*)hp = *(const uint4*)h;
  *(uint4*)lp = *(const uint4*)l;
}

// Q,K projection (cols 0..2047 of qkv): fp64 accumulation via
// v_mfma_f64_16x16x4 (matrix pipe). Per-wave k-order is ascending 0..1023 in
// 4-k steps — BIT-IDENTICAL accumulation to the round-3/4 passing path
// (top-k selection depends on these exact fp32-rounded bits).
// Round-5 lesson: do NOT fuse V into this kernel — f64 and bf16 MFMA share
// one matrix pipe, fusion lengthens the critical path.
// This round: BK=64 (was 32) halves barrier count — the ~27% pipe-idle was
// barrier drain (2 barriers x 32 chunks). LDS 34.8KB -> 4 blocks/CU.
// C/D layout decoded at runtime with probe MFMAs (round-2 lesson).
// Also emits kbf: bf16 K image, XOR-swizzled for attn's linear LDS staging.
__global__ __launch_bounds__(256) void gemm_qk(
    const float* __restrict__ A, const float* __restrict__ Bm,
    float* __restrict__ qbuf, float* __restrict__ kbuf,
    unsigned short* __restrict__ kbf) {
  __shared__ __align__(16) float As[64][68];   // row-major, +4 pad
  __shared__ __align__(16) float Bs[64][68];
  const int tid = threadIdx.x;
  const int lane = tid & 63;
  const int w = tid >> 6;
  const int row0 = blockIdx.y * 64;
  const int col0 = blockIdx.x * 64;
  const int lrow = tid >> 2;        // 0..63
  const int lk = (tid & 3) << 4;    // 0,16,32,48
  const float* ap = A + (size_t)(row0 + lrow) * KDIM + lk;
  const float* bp = Bm + (size_t)(col0 + lrow) * KDIM + lk;
  const int wr = (w >> 1) << 5;     // 0 or 32 (row offset)
  const int wc = (w & 1) << 5;      // 0 or 32 (col offset)
  const int li = lane & 15;         // A row / B col within subtile
  const int lk4 = lane >> 4;        // k within 4-step (A/B frag)

  // ---- C/D layout probe: decode (row,col) of each acc slot at runtime ----
  int rowof[4], colof[4];
  {
    f64x4v pr = {0.0, 0.0, 0.0, 0.0};
    f64x4v pc = {0.0, 0.0, 0.0, 0.0};
    const double vidx = (double)li;
    pr = __builtin_amdgcn_mfma_f64_16x16x4f64(vidx, 1.0, pr, 0, 0, 0);
    pc = __builtin_amdgcn_mfma_f64_16x16x4f64(1.0, vidx, pc, 0, 0, 0);
#pragma unroll
    for (int vj = 0; vj < 4; ++vj) {
      rowof[vj] = (int)(pr[vj] * 0.25 + 0.5);
      colof[vj] = (int)(pc[vj] * 0.25 + 0.5);
    }
  }

  f64x4v acc[2][2];
#pragma unroll
  for (int m = 0; m < 2; ++m)
#pragma unroll
    for (int n = 0; n < 2; ++n)
      acc[m][n] = (f64x4v){0.0, 0.0, 0.0, 0.0};

  // register prefetch one 64-k chunk ahead
  float4 ra[4], rb[4];
#pragma unroll
  for (int i = 0; i < 4; ++i) {
    ra[i] = *(const float4*)(ap + 4 * i);
    rb[i] = *(const float4*)(bp + 4 * i);
  }
  for (int k0 = 0; k0 < KDIM; k0 += 64) {
    __syncthreads();   // previous chunk's readers done
#pragma unroll
    for (int i = 0; i < 4; ++i) {
      *(float4*)&As[lrow][lk + 4 * i] = ra[i];
      *(float4*)&Bs[lrow][lk + 4 * i] = rb[i];
    }
    if (k0 + 64 < KDIM) {
#pragma unroll
      for (int i = 0; i < 4; ++i) {
        ra[i] = *(const float4*)(ap + k0 + 64 + 4 * i);
        rb[i] = *(const float4*)(bp + k0 + 64 + 4 * i);
      }
    }
    __syncthreads();
#pragma unroll
    for (int ks = 0; ks < 64; ks += 4) {
      const int kk = ks + lk4;
      const double af0 = (double)As[wr + li][kk];
      const double af1 = (double)As[wr + 16 + li][kk];
      const double bf0 = (double)Bs[wc + li][kk];
      const double bf1 = (double)Bs[wc + 16 + li][kk];
      acc[0][0] = __builtin_amdgcn_mfma_f64_16x16x4f64(af0, bf0, acc[0][0], 0, 0, 0);
      acc[0][1] = __builtin_amdgcn_mfma_f64_16x16x4f64(af0, bf1, acc[0][1], 0, 0, 0);
      acc[1][0] = __builtin_amdgcn_mfma_f64_16x16x4f64(af1, bf0, acc[1][0], 0, 0, 0);
      acc[1][1] = __builtin_amdgcn_mfma_f64_16x16x4f64(af1, bf1, acc[1][1], 0, 0, 0);
    }
  }

  const int qi = col0 >> 10;            // 0=q 1=k
  const int head = (col0 & 1023) >> 6;
  const int bb = row0 >> 11;
  const int t0 = row0 & 2047;
  const size_t base = (size_t)(bb * NH + head) * SEQ_T * DH;
  float* dst = ((qi == 0) ? qbuf : kbuf) + base;
  unsigned short* kb = kbf + ((size_t)(bb * NH + head) << 17);  // 16*8192
#pragma unroll
  for (int m = 0; m < 2; ++m)
#pragma unroll
    for (int n = 0; n < 2; ++n)
#pragma unroll
      for (int vj = 0; vj < 4; ++vj) {
        const int r = wr + 16 * m + rowof[vj];      // row in tile (0..63)
        const int dcol = wc + 16 * n + colof[vj];   // col in tile (0..63)
        const int t = t0 + r;
        const float fv = (float)acc[m][n][vj];
        dst[(size_t)t * DH + dcol] = fv;
        if (qi == 1) {
          const int key = t & 127;
          const int off =
              (((t >> 7) << 13) | (key << 6) | dcol) ^ ((key & 7) << 3);
          __hip_bfloat16 hb = __float2bfloat16(fv);
          kb[off] = *(unsigned short*)&hb;
        }
      }
}

// V projection (cols 2048..3071): split-bf16 MFMA (round-4 passing version).
// C = Ah*Bh + Ah*Bl + Al*Bh; dropped lo*lo ~1.6e-5 rel, invisible at V's
// bf16 granularity. Bm passed pre-offset to wqkv + 2048*KDIM.
__global__ __launch_bounds__(256) void gemm_v(
    const float* __restrict__ A, const float* __restrict__ Bm,
    unsigned short* __restrict__ vbuf) {
  __shared__ __align__(16) unsigned short Ah[64][40];  // rows padded to 80B
  __shared__ __align__(16) unsigned short Al[64][40];
  __shared__ __align__(16) unsigned short Bh[64][40];
  __shared__ __align__(16) unsigned short Bl[64][40];
  const int tid = threadIdx.x;
  const int lane = tid & 63;
  const int w = tid >> 6;
  const int row0 = blockIdx.y * 64;
  const int col0 = blockIdx.x * 64;
  const int lrow = tid >> 2;
  const int lk = (tid & 3) << 3;
  const float* ap = A + (size_t)(row0 + lrow) * KDIM + lk;
  const float* bp = Bm + (size_t)(col0 + lrow) * KDIM + lk;
  const int wr = (w >> 1) << 5;
  const int wc = (w & 1) << 5;
  const int li = lane & 15;
  const int kA = (lane >> 4) << 3;   // frag k-run: k = kA + j (verified map)

  f32x4v acc[2][2];
#pragma unroll
  for (int m = 0; m < 2; ++m)
#pragma unroll
    for (int n = 0; n < 2; ++n)
      acc[m][n] = (f32x4v){0.f, 0.f, 0.f, 0.f};

  float4 ra0 = *(const float4*)(ap);
  float4 ra1 = *(const float4*)(ap + 4);
  float4 rb0 = *(const float4*)(bp);
  float4 rb1 = *(const float4*)(bp + 4);
  for (int k0 = 0; k0 < KDIM; k0 += 32) {
    __syncthreads();
    split8(ra0, ra1, &Ah[lrow][lk], &Al[lrow][lk]);
    split8(rb0, rb1, &Bh[lrow][lk], &Bl[lrow][lk]);
    if (k0 + 32 < KDIM) {
      ra0 = *(const float4*)(ap + k0 + 32);
      ra1 = *(const float4*)(ap + k0 + 36);
      rb0 = *(const float4*)(bp + k0 + 32);
      rb1 = *(const float4*)(bp + k0 + 36);
    }
    __syncthreads();
    bf16x8v ah[2], al[2], bh[2], bl[2];
#pragma unroll
    for (int m = 0; m < 2; ++m) {
      ah[m] = *(const bf16x8v*)&Ah[wr + 16 * m + li][kA];
      al[m] = *(const bf16x8v*)&Al[wr + 16 * m + li][kA];
      bh[m] = *(const bf16x8v*)&Bh[wc + 16 * m + li][kA];
      bl[m] = *(const bf16x8v*)&Bl[wc + 16 * m + li][kA];
    }
#pragma unroll
    for (int m = 0; m < 2; ++m)
#pragma unroll
      for (int n = 0; n < 2; ++n) {
        acc[m][n] = __builtin_amdgcn_mfma_f32_16x16x32_bf16(ah[m], bh[n], acc[m][n], 0, 0, 0);
        acc[m][n] = __builtin_amdgcn_mfma_f32_16x16x32_bf16(ah[m], bl[n], acc[m][n], 0, 0, 0);
        acc[m][n] = __builtin_amdgcn_mfma_f32_16x16x32_bf16(al[m], bh[n], acc[m][n], 0, 0, 0);
      }
  }

  const int head = col0 >> 6;  // col0 in 0..1023 here; tile within one head
  const int bb = row0 >> 11;
  const int t0 = row0 & 2047;
  unsigned short* dst = vbuf + (size_t)(bb * NH + head) * SEQ_T * DH;
  const int r4 = (lane >> 4) << 2;  // C row base (verified bf16 C layout)
#pragma unroll
  for (int m = 0; m < 2; ++m)
#pragma unroll
    for (int n = 0; n < 2; ++n)
#pragma unroll
      for (int j = 0; j < 4; ++j) {
        const int t = t0 + wr + 16 * m + r4 + j;
        const int d = wc + 16 * n + li;
        dst[(size_t)t * DH + d] = (unsigned short)f2bs(acc[m][n][j]);
      }
}

// Attention, MFMA candidate-filter scheme. Passes 1/2 and phases 3A/3B are
// the round-1-verified code; phase 3C uses round-5's 4 interleaved
// independent row-chains (4 V-loads in flight), per-row summation order
// unchanged (bit-identical output).
__global__ __launch_bounds__(256) void attn_topk(
    const float* __restrict__ q, const float* __restrict__ kmat,
    const unsigned short* __restrict__ kbf,
    const unsigned short* __restrict__ v, unsigned short* __restrict__ ctx) {
  __shared__ __align__(16) unsigned short kt[128 * 64];  // 16KB swizzled tile
  __shared__ double cs64[64][CAP];                       // 16KB exact scores
  __shared__ short ckey[64][CAP];                        // 4KB candidate keys
  __shared__ int ccnt[64];
  __shared__ double rthr[64];
  __shared__ float rmx[64];

  const int tid = threadIdx.x;
  const int lane = tid & 63;
  const int w = tid >> 6;
  const int bh = blockIdx.x & 31;
  const int t0 = (blockIdx.x >> 5) << 6;
  const size_t kbase = (size_t)bh * SEQ_T * DH;
  const int wrow0 = t0 + (w << 4);
  const int kA = (lane >> 4) << 3;                 // A/B-frag k-run offset
  const int rbase = wrow0 + ((lane >> 4) << 2);    // C row of acc[0]

  // Q fragment (A operand): row = lane&15, k = 8*(lane>>4)+j (+32 for half 1)
  bf16x8v qa0, qa1;
  {
    const float* qr = q + kbase + (size_t)(wrow0 + (lane & 15)) * DH;
    const float4 x0 = *(const float4*)(qr + kA);
    const float4 x1 = *(const float4*)(qr + kA + 4);
    const float4 y0 = *(const float4*)(qr + 32 + kA);
    const float4 y1 = *(const float4*)(qr + 32 + kA + 4);
    qa0[0] = f2bs(x0.x); qa0[1] = f2bs(x0.y);
    qa0[2] = f2bs(x0.z); qa0[3] = f2bs(x0.w);
    qa0[4] = f2bs(x1.x); qa0[5] = f2bs(x1.y);
    qa0[6] = f2bs(x1.z); qa0[7] = f2bs(x1.w);
    qa1[0] = f2bs(y0.x); qa1[1] = f2bs(y0.y);
    qa1[2] = f2bs(y0.z); qa1[3] = f2bs(y0.w);
    qa1[4] = f2bs(y1.x); qa1[5] = f2bs(y1.y);
    qa1[6] = f2bs(y1.z); qa1[7] = f2bs(y1.w);
  }

  const uint4* ksrc = (const uint4*)(kbf + ((size_t)bh << 17));
  const int nt = (t0 >> 7) + 1;       // tiles covering keys 0..t0+63
  const int wmax = wrow0 + 15;

  float tq[4][8];
#pragma unroll
  for (int j = 0; j < 4; ++j)
#pragma unroll
    for (int m = 0; m < 8; ++m) tq[j][m] = -FLT_MAX;

  // ---- pass 1: MFMA scores + per-lane top-8 per slot ----
  for (int T = 0; T < nt; ++T) {
    if (T) __syncthreads();
    {
      const uint4* st = ksrc + (size_t)T * 1024;
      uint4* dv = (uint4*)kt;
#pragma unroll
      for (int i = 0; i < 4; ++i) dv[i * 256 + tid] = st[i * 256 + tid];
    }
    __syncthreads();
    const int glim0 = (wmax - (T << 7)) >> 4;
    const int glim = glim0 > 7 ? 7 : glim0;
    for (int gt = 0; gt <= glim; ++gt) {
      const int kk = (gt << 4) + (lane & 15);
      const int key = (T << 7) + kk;
      const int b0 = ((kk << 7) | (kA << 1)) ^ ((kk & 7) << 4);
      const int b1 = ((kk << 7) | ((32 + kA) << 1)) ^ ((kk & 7) << 4);
      const bf16x8v kb0 = *(const bf16x8v*)((const char*)kt + b0);
      const bf16x8v kb1 = *(const bf16x8v*)((const char*)kt + b1);
      f32x4v acc = {0.f, 0.f, 0.f, 0.f};
      acc = __builtin_amdgcn_mfma_f32_16x16x32_bf16(qa0, kb0, acc, 0, 0, 0);
      acc = __builtin_amdgcn_mfma_f32_16x16x32_bf16(qa1, kb1, acc, 0, 0, 0);
#pragma unroll
      for (int j = 0; j < 4; ++j) {
        float sc = acc[j] * 0.125f;
        sc = (key <= rbase + j) ? sc : -FLT_MAX;
        if (sc > tq[j][7]) {
          float s = sc;
#pragma unroll
          for (int m = 0; m < 8; ++m) {
            const float hi = fmaxf(tq[j][m], s);
            s = fminf(tq[j][m], s);
            tq[j][m] = hi;
          }
        }
      }
    }
  }

  // ---- merge per slot across the 16-lane group (4 bitonic rounds) ----
#pragma unroll
  for (int j = 0; j < 4; ++j) {
#pragma unroll
    for (int xm = 1; xm < 16; xm <<= 1) {
      float m[8];
#pragma unroll
      for (int i = 0; i < 8; ++i) {
        const float pb = __shfl_xor(tq[j][7 - i], xm);
        m[i] = fmaxf(tq[j][i], pb);
      }
#pragma unroll
      for (int d = 4; d >= 1; d >>= 1)
#pragma unroll
        for (int i = 0; i < 8; ++i)
          if ((i & d) == 0 && (i | d) < 8) {
            const float hi = fmaxf(m[i], m[i | d]);
            const float lo = fminf(m[i], m[i | d]);
            m[i] = hi;
            m[i | d] = lo;
          }
#pragma unroll
      for (int i = 0; i < 8; ++i) tq[j][i] = m[i];
    }
  }
  float thrj[4];
#pragma unroll
  for (int j = 0; j < 4; ++j) {
    const int kf = (rbase + j + 1 < KSEL) ? (rbase + j + 1) : KSEL;
    float th = tq[j][7];
#pragma unroll
    for (int m = 0; m < 8; ++m)
      if (m == kf - 1) th = tq[j][m];
    thrj[j] = th - MFMA_MARGIN;
  }

  if (tid < 64) ccnt[tid] = 0;
  __syncthreads();

  // ---- pass 2: identical MFMA re-scan, collect candidates ----
  for (int T = 0; T < nt; ++T) {
    if (T) __syncthreads();
    {
      const uint4* st = ksrc + (size_t)T * 1024;
      uint4* dv = (uint4*)kt;
#pragma unroll
      for (int i = 0; i < 4; ++i) dv[i * 256 + tid] = st[i * 256 + tid];
    }
    __syncthreads();
    const int glim0 = (wmax - (T << 7)) >> 4;
    const int glim = glim0 > 7 ? 7 : glim0;
    for (int gt = 0; gt <= glim; ++gt) {
      const int kk = (gt << 4) + (lane & 15);
      const int key = (T << 7) + kk;
      const int b0 = ((kk << 7) | (kA << 1)) ^ ((kk & 7) << 4);
      const int b1 = ((kk << 7) | ((32 + kA) << 1)) ^ ((kk & 7) << 4);
      const bf16x8v kb0 = *(const bf16x8v*)((const char*)kt + b0);
      const bf16x8v kb1 = *(const bf16x8v*)((const char*)kt + b1);
      f32x4v acc = {0.f, 0.f, 0.f, 0.f};
      acc = __builtin_amdgcn_mfma_f32_16x16x32_bf16(qa0, kb0, acc, 0, 0, 0);
      acc = __builtin_amdgcn_mfma_f32_16x16x32_bf16(qa1, kb1, acc, 0, 0, 0);
#pragma unroll
      for (int j = 0; j < 4; ++j) {
        const float sc = acc[j] * 0.125f;
        if (key <= rbase + j && sc >= thrj[j]) {
          const int rl = (w << 4) + ((lane >> 4) << 2) + j;
          const int p = atomicAdd(&ccnt[rl], 1);
          if (p < CAP) ckey[rl][p] = (short)key;
        }
      }
    }
  }

  // ---- phase 3A: exact fp64 rescore, lane-per-candidate, 2 rows/iter ----
  const int lid = lane & 31;
  for (int rp = 0; rp < 8; ++rp) {
    const int rl = (w << 4) + (rp << 1) + (lane >> 5);
    const int ncc = ccnt[rl] < CAP ? ccnt[rl] : CAP;
    if (lid < ncc) {
      const int key = ckey[rl][lid];
      const float* qr = q + kbase + (size_t)(t0 + rl) * DH;
      const float* kr = kmat + kbase + (size_t)key * DH;
      double s = 0.0;
#pragma unroll
      for (int d4 = 0; d4 < 16; ++d4) {
        const float4 qq = *(const float4*)(qr + (d4 << 2));
        const float4 kq = *(const float4*)(kr + (d4 << 2));
        s = fma((double)qq.x, (double)kq.x, s);
        s = fma((double)qq.y, (double)kq.y, s);
        s = fma((double)qq.z, (double)kq.z, s);
        s = fma((double)qq.w, (double)kq.w, s);
      }
      cs64[rl][lid] = s * 0.125;
    }
  }
  __syncthreads();

  // ---- phase 3B: per-row fp64 top-8 + threshold (row per lane) ----
  if (lane < 16) {
    const int rl = (w << 4) + lane;
    const int trow = t0 + rl;
    const int ncc = ccnt[rl] < CAP ? ccnt[rl] : CAP;
    double a64[8];
#pragma unroll
    for (int j = 0; j < 8; ++j) a64[j] = -DBL_MAX;
    for (int l = 0; l < ncc; ++l) {
      double sv = cs64[rl][l];
#pragma unroll
      for (int j = 0; j < 8; ++j) {
        const double hi = fmax(a64[j], sv);
        sv = fmin(a64[j], sv);
        a64[j] = hi;
      }
    }
    const int kf = (trow + 1 < KSEL) ? (trow + 1) : KSEL;
    double th = a64[7];
#pragma unroll
    for (int j = 0; j < 8; ++j)
      if (j == kf - 1) th = a64[j];
    rthr[rl] = th;
    rmx[rl] = (float)a64[0];
  }
  __syncthreads();

  // ---- phase 3C: sparse softmax * V, 4 interleaved row-chains ----
  for (int rg = 0; rg < 4; ++rg) {
    const int rlb = (w << 4) + (rg << 2);
    float acv[4] = {0.f, 0.f, 0.f, 0.f};
    float Zs[4] = {0.f, 0.f, 0.f, 0.f};
    int ncs[4];
    double ths[4];
    float mxs[4];
#pragma unroll
    for (int j = 0; j < 4; ++j) {
      const int rl = rlb + j;
      ncs[j] = ccnt[rl] < CAP ? ccnt[rl] : CAP;
      ths[j] = rthr[rl];
      mxs[j] = rmx[rl];
    }
    int nmax = ncs[0];
#pragma unroll
    for (int j = 1; j < 4; ++j) nmax = ncs[j] > nmax ? ncs[j] : nmax;
    for (int l = 0; l < nmax; ++l) {
#pragma unroll
      for (int j = 0; j < 4; ++j) {
        const int rl = rlb + j;
        if (l < ncs[j]) {
          const double s = cs64[rl][l];
          const float wgl = (s >= ths[j]) ? expf((float)s - mxs[j]) : 0.f;
          Zs[j] += wgl;
          acv[j] = fmaf(
              wgl,
              bf2f((unsigned int)v[kbase + (size_t)ckey[rl][l] * DH + lane]),
              acv[j]);
        }
      }
    }
#pragma unroll
    for (int j = 0; j < 4; ++j) {
      const int trow = t0 + rlb + j;
      __hip_bfloat16 h = __float2bfloat16(acv[j] / Zs[j]);
      ctx[((size_t)(bh >> 4) * SEQ_T + trow) * DIM_D + (bh & 15) * DH + lane] =
          *(unsigned short*)&h;
    }
  }
}

// Output projection via MFMA: A = ctx (exactly bf16), B = wout split to
// hi+lo bf16; C = A*Bh + A*Bl in fp32 accumulators (~1.6e-5 rel error vs
// fp32 chain — output threshold is 0.0765).
__global__ __launch_bounds__(256) void gemm_out(
    const unsigned short* __restrict__ A, const float* __restrict__ Bm,
    float* __restrict__ obuf) {
  __shared__ __align__(16) unsigned short Ah[64][40];
  __shared__ __align__(16) unsigned short Bh[64][40];
  __shared__ __align__(16) unsigned short Bl[64][40];
  const int tid = threadIdx.x;
  const int lane = tid & 63;
  const int w = tid >> 6;
  const int row0 = blockIdx.y * 64;
  const int col0 = blockIdx.x * 64;
  const int lrow = tid >> 2;
  const int lk = (tid & 3) << 3;
  const unsigned short* ap = A + (size_t)(row0 + lrow) * KDIM + lk;
  const float* bp = Bm + (size_t)(col0 + lrow) * KDIM + lk;
  const int wr = (w >> 1) << 5;
  const int wc = (w & 1) << 5;
  const int li = lane & 15;
  const int kA = (lane >> 4) << 3;

  f32x4v acc[2][2];
#pragma unroll
  for (int m = 0; m < 2; ++m)
#pragma unroll
    for (int n = 0; n < 2; ++n)
      acc[m][n] = (f32x4v){0.f, 0.f, 0.f, 0.f};

  uint4 ua = *(const uint4*)(ap);
  float4 rb0 = *(const float4*)(bp);
  float4 rb1 = *(const float4*)(bp + 4);
  for (int k0 = 0; k0 < KDIM; k0 += 32) {
    __syncthreads();
    *(uint4*)&Ah[lrow][lk] = ua;
    split8(rb0, rb1, &Bh[lrow][lk], &Bl[lrow][lk]);
    if (k0 + 32 < KDIM) {
      ua = *(const uint4*)(ap + k0 + 32);
      rb0 = *(const float4*)(bp + k0 + 32);
      rb1 = *(const float4*)(bp + k0 + 36);
    }
    __syncthreads();
    bf16x8v ah[2], bh[2], bl[2];
#pragma unroll
    for (int m = 0; m < 2; ++m) {
      ah[m] = *(const bf16x8v*)&Ah[wr + 16 * m + li][kA];
      bh[m] = *(const bf16x8v*)&Bh[wc + 16 * m + li][kA];
      bl[m] = *(const bf16x8v*)&Bl[wc + 16 * m + li][kA];
    }
#pragma unroll
    for (int m = 0; m < 2; ++m)
#pragma unroll
      for (int n = 0; n < 2; ++n) {
        acc[m][n] = __builtin_amdgcn_mfma_f32_16x16x32_bf16(ah[m], bh[n], acc[m][n], 0, 0, 0);
        acc[m][n] = __builtin_amdgcn_mfma_f32_16x16x32_bf16(ah[m], bl[n], acc[m][n], 0, 0, 0);
      }
  }

  const int r4 = (lane >> 4) << 2;
#pragma unroll
  for (int m = 0; m < 2; ++m)
#pragma unroll
    for (int n = 0; n < 2; ++n)
#pragma unroll
      for (int j = 0; j < 4; ++j) {
        const int r = row0 + wr + 16 * m + r4 + j;
        const int c = col0 + wc + 16 * n + li;
        obuf[(size_t)r * DIM_D + c] = acc[m][n][j];
      }
}

extern "C" void kernel_launch(void* const* d_in, const int* in_sizes, int n_in,
                              void* d_out, int out_size, void* d_ws,
                              size_t ws_size, hipStream_t stream) {
  (void)out_size; (void)ws_size;
  const float* x = (const float*)d_in[0];
  const float* wqkv = (const float*)d_in[1];
  const float* wout = (const float*)d_in[2];
  for (int i = 0; i < n_in; ++i) {
    if (in_sizes[i] == NUM_B * SEQ_T * DIM_D) x = (const float*)d_in[i];
    else if (in_sizes[i] == 3 * DIM_D * DIM_D) wqkv = (const float*)d_in[i];
    else if (in_sizes[i] == DIM_D * DIM_D) wout = (const float*)d_in[i];
  }
  float* out = (float*)d_out;

  const size_t qkv_elems = (size_t)NUM_B * NH * SEQ_T * DH;   // 4.19M
  float* qbuf = (float*)d_ws;
  float* kbuf = qbuf + qkv_elems;
  unsigned short* vbuf = (unsigned short*)(kbuf + qkv_elems);
  unsigned short* ctxb = vbuf + qkv_elems;
  unsigned short* kbf = ctxb + (size_t)NUM_B * SEQ_T * DIM_D;  // bf16 K tiles

  gemm_qk<<<dim3(2 * DIM_D / 64, NUM_B * SEQ_T / 64), 256, 0, stream>>>(
      x, wqkv, qbuf, kbuf, kbf);
  gemm_v<<<dim3(DIM_D / 64, NUM_B * SEQ_T / 64), 256, 0, stream>>>(
      x, wqkv + (size_t)2 * DIM_D * KDIM, vbuf);
  attn_topk<<<dim3(NUM_B * NH * (SEQ_T / 64)), 256, 0, stream>>>(
      qbuf, kbuf, kbf, vbuf, ctxb);
  gemm_out<<<dim3(DIM_D / 64, NUM_B * SEQ_T / 64), 256, 0, stream>>>(
      ctxb, wout, out);
}

// Round 7
// 671.042 us; speedup vs baseline: 1.1233x; 1.1233x over previous
//
#include <hip/hip_runtime.h>
#include <hip/hip_bf16.h>
#include <math.h>
#include <float.h>

#define NUM_B 2
#define SEQ_T 2048
#define DIM_D 1024
#define NH 16
#define DH 64
#define KDIM 1024
#define KSEL 8

// attention candidate scheme
#define CAP 32
#define MFMA_MARGIN 0.06f

typedef __attribute__((ext_vector_type(8))) short bf16x8v;   // 8 bf16 (4 VGPR)
typedef __attribute__((ext_vector_type(4))) float f32x4v;    // MFMA acc
typedef __attribute__((ext_vector_type(4))) double f64x4v;   // f64 MFMA acc

__device__ __forceinline__ float bf2f(unsigned int u) {
  union { unsigned int i; float f; } v; v.i = u << 16; return v.f;
}

__device__ __forceinline__ short f2bs(float f) {
  __hip_bfloat16 h = __float2bfloat16(f);
  return *(short*)&h;
}

// split x into hi+lo bf16 (residual ~1.6e-5 rel); store 8 to LDS as 16B each
__device__ __forceinline__ void split8(float4 x0, float4 x1,
                                       unsigned short* __restrict__ hp,
                                       unsigned short* __restrict__ lp) {
  unsigned short h[8], l[8];
  const float xs[8] = {x0.x, x0.y, x0.z, x0.w, x1.x, x1.y, x1.z, x1.w};
#pragma unroll
  for (int j = 0; j < 8; ++j) {
    const short hb = f2bs(xs[j]);
    h[j] = (unsigned short)hb;
    const float hf = bf2f((unsigned int)(unsigned short)hb);
    l[j] = (unsigned short)f2bs(xs[j] - hf);
  }
  *(uint4*)hp = *(const uint4*)h;
  *(uint4*)lp = *(const uint4*)l;
}

// Q,K projection (cols 0..2047 of qkv): fp64 accumulation via
// v_mfma_f64_16x16x4. Per-wave k-order ascending 0..1023 in 4-k steps —
// BIT-IDENTICAL to the round-3/4 passing path (selection-critical).
// Round-6 lesson: BK=64's 8-float4 prefetch spilled to scratch (~1GB
// writes). This version: BK=32, DOUBLE-BUFFERED LDS, ONE barrier per chunk
// (32 instead of 64 barrier drains), carrying only the 16 VGPRs round-4
// held spill-free. Write-parity safety: at iter c we write buf[(c+1)&1],
// whose readers finished before the barrier ending iter c-1.
// C/D layout decoded at runtime with probe MFMAs (round-2 lesson).
// Also emits kbf: bf16 K image, XOR-swizzled for attn's linear staging.
__global__ __launch_bounds__(256) void gemm_qk(
    const float* __restrict__ A, const float* __restrict__ Bm,
    float* __restrict__ qbuf, float* __restrict__ kbuf,
    unsigned short* __restrict__ kbf) {
  __shared__ __align__(16) float As[2][64][36];   // row-major, +4 pad
  __shared__ __align__(16) float Bs[2][64][36];
  const int tid = threadIdx.x;
  const int lane = tid & 63;
  const int w = tid >> 6;
  const int row0 = blockIdx.y * 64;
  const int col0 = blockIdx.x * 64;
  const int lrow = tid >> 2;        // 0..63
  const int lk = (tid & 3) << 3;    // 0,8,16,24
  const float* ap = A + (size_t)(row0 + lrow) * KDIM + lk;
  const float* bp = Bm + (size_t)(col0 + lrow) * KDIM + lk;
  const int wr = (w >> 1) << 5;     // 0 or 32 (row offset)
  const int wc = (w & 1) << 5;      // 0 or 32 (col offset)
  const int li = lane & 15;         // A row / B col within subtile
  const int lk4 = lane >> 4;        // k within 4-step (A/B frag)

  // ---- C/D layout probe: decode (row,col) of each acc slot at runtime ----
  int rowof[4], colof[4];
  {
    f64x4v pr = {0.0, 0.0, 0.0, 0.0};
    f64x4v pc = {0.0, 0.0, 0.0, 0.0};
    const double vidx = (double)li;
    pr = __builtin_amdgcn_mfma_f64_16x16x4f64(vidx, 1.0, pr, 0, 0, 0);
    pc = __builtin_amdgcn_mfma_f64_16x16x4f64(1.0, vidx, pc, 0, 0, 0);
#pragma unroll
    for (int vj = 0; vj < 4; ++vj) {
      rowof[vj] = (int)(pr[vj] * 0.25 + 0.5);
      colof[vj] = (int)(pc[vj] * 0.25 + 0.5);
    }
  }

  f64x4v acc[2][2];
#pragma unroll
  for (int m = 0; m < 2; ++m)
#pragma unroll
    for (int n = 0; n < 2; ++n)
      acc[m][n] = (f64x4v){0.0, 0.0, 0.0, 0.0};

  // prologue: stage chunk 0 into buffer 0
  float4 ra0 = *(const float4*)(ap);
  float4 ra1 = *(const float4*)(ap + 4);
  float4 rb0 = *(const float4*)(bp);
  float4 rb1 = *(const float4*)(bp + 4);
  *(float4*)&As[0][lrow][lk] = ra0;
  *(float4*)&As[0][lrow][lk + 4] = ra1;
  *(float4*)&Bs[0][lrow][lk] = rb0;
  *(float4*)&Bs[0][lrow][lk + 4] = rb1;
  __syncthreads();

  for (int c = 0; c < 32; ++c) {
    const int cur = c & 1;
    if (c + 1 < 32) {
      const int kn = (c + 1) << 5;
      ra0 = *(const float4*)(ap + kn);
      ra1 = *(const float4*)(ap + kn + 4);
      rb0 = *(const float4*)(bp + kn);
      rb1 = *(const float4*)(bp + kn + 4);
    }
#pragma unroll
    for (int ks = 0; ks < 32; ks += 4) {
      const int kk = ks + lk4;
      const double af0 = (double)As[cur][wr + li][kk];
      const double af1 = (double)As[cur][wr + 16 + li][kk];
      const double bf0 = (double)Bs[cur][wc + li][kk];
      const double bf1 = (double)Bs[cur][wc + 16 + li][kk];
      acc[0][0] = __builtin_amdgcn_mfma_f64_16x16x4f64(af0, bf0, acc[0][0], 0, 0, 0);
      acc[0][1] = __builtin_amdgcn_mfma_f64_16x16x4f64(af0, bf1, acc[0][1], 0, 0, 0);
      acc[1][0] = __builtin_amdgcn_mfma_f64_16x16x4f64(af1, bf0, acc[1][0], 0, 0, 0);
      acc[1][1] = __builtin_amdgcn_mfma_f64_16x16x4f64(af1, bf1, acc[1][1], 0, 0, 0);
    }
    if (c + 1 < 32) {
      const int nxt = cur ^ 1;
      *(float4*)&As[nxt][lrow][lk] = ra0;
      *(float4*)&As[nxt][lrow][lk + 4] = ra1;
      *(float4*)&Bs[nxt][lrow][lk] = rb0;
      *(float4*)&Bs[nxt][lrow][lk + 4] = rb1;
    }
    __syncthreads();
  }

  const int qi = col0 >> 10;            // 0=q 1=k
  const int head = (col0 & 1023) >> 6;
  const int bb = row0 >> 11;
  const int t0 = row0 & 2047;
  const size_t base = (size_t)(bb * NH + head) * SEQ_T * DH;
  float* dst = ((qi == 0) ? qbuf : kbuf) + base;
  unsigned short* kb = kbf + ((size_t)(bb * NH + head) << 17);  // 16*8192
#pragma unroll
  for (int m = 0; m < 2; ++m)
#pragma unroll
    for (int n = 0; n < 2; ++n)
#pragma unroll
      for (int vj = 0; vj < 4; ++vj) {
        const int r = wr + 16 * m + rowof[vj];      // row in tile (0..63)
        const int dcol = wc + 16 * n + colof[vj];   // col in tile (0..63)
        const int t = t0 + r;
        const float fv = (float)acc[m][n][vj];
        dst[(size_t)t * DH + dcol] = fv;
        if (qi == 1) {
          const int key = t & 127;
          const int off =
              (((t >> 7) << 13) | (key << 6) | dcol) ^ ((key & 7) << 3);
          __hip_bfloat16 hb = __float2bfloat16(fv);
          kb[off] = *(unsigned short*)&hb;
        }
      }
}

// V projection (cols 2048..3071): split-bf16 MFMA (round-4 passing version).
// C = Ah*Bh + Ah*Bl + Al*Bh; dropped lo*lo ~1.6e-5 rel, invisible at V's
// bf16 granularity. Bm passed pre-offset to wqkv + 2048*KDIM.
__global__ __launch_bounds__(256) void gemm_v(
    const float* __restrict__ A, const float* __restrict__ Bm,
    unsigned short* __restrict__ vbuf) {
  __shared__ __align__(16) unsigned short Ah[64][40];  // rows padded to 80B
  __shared__ __align__(16) unsigned short Al[64][40];
  __shared__ __align__(16) unsigned short Bh[64][40];
  __shared__ __align__(16) unsigned short Bl[64][40];
  const int tid = threadIdx.x;
  const int lane = tid & 63;
  const int w = tid >> 6;
  const int row0 = blockIdx.y * 64;
  const int col0 = blockIdx.x * 64;
  const int lrow = tid >> 2;
  const int lk = (tid & 3) << 3;
  const float* ap = A + (size_t)(row0 + lrow) * KDIM + lk;
  const float* bp = Bm + (size_t)(col0 + lrow) * KDIM + lk;
  const int wr = (w >> 1) << 5;
  const int wc = (w & 1) << 5;
  const int li = lane & 15;
  const int kA = (lane >> 4) << 3;   // frag k-run: k = kA + j (verified map)

  f32x4v acc[2][2];
#pragma unroll
  for (int m = 0; m < 2; ++m)
#pragma unroll
    for (int n = 0; n < 2; ++n)
      acc[m][n] = (f32x4v){0.f, 0.f, 0.f, 0.f};

  float4 ra0 = *(const float4*)(ap);
  float4 ra1 = *(const float4*)(ap + 4);
  float4 rb0 = *(const float4*)(bp);
  float4 rb1 = *(const float4*)(bp + 4);
  for (int k0 = 0; k0 < KDIM; k0 += 32) {
    __syncthreads();
    split8(ra0, ra1, &Ah[lrow][lk], &Al[lrow][lk]);
    split8(rb0, rb1, &Bh[lrow][lk], &Bl[lrow][lk]);
    if (k0 + 32 < KDIM) {
      ra0 = *(const float4*)(ap + k0 + 32);
      ra1 = *(const float4*)(ap + k0 + 36);
      rb0 = *(const float4*)(bp + k0 + 32);
      rb1 = *(const float4*)(bp + k0 + 36);
    }
    __syncthreads();
    bf16x8v ah[2], al[2], bh[2], bl[2];
#pragma unroll
    for (int m = 0; m < 2; ++m) {
      ah[m] = *(const bf16x8v*)&Ah[wr + 16 * m + li][kA];
      al[m] = *(const bf16x8v*)&Al[wr + 16 * m + li][kA];
      bh[m] = *(const bf16x8v*)&Bh[wc + 16 * m + li][kA];
      bl[m] = *(const bf16x8v*)&Bl[wc + 16 * m + li][kA];
    }
#pragma unroll
    for (int m = 0; m < 2; ++m)
#pragma unroll
      for (int n = 0; n < 2; ++n) {
        acc[m][n] = __builtin_amdgcn_mfma_f32_16x16x32_bf16(ah[m], bh[n], acc[m][n], 0, 0, 0);
        acc[m][n] = __builtin_amdgcn_mfma_f32_16x16x32_bf16(ah[m], bl[n], acc[m][n], 0, 0, 0);
        acc[m][n] = __builtin_amdgcn_mfma_f32_16x16x32_bf16(al[m], bh[n], acc[m][n], 0, 0, 0);
      }
  }

  const int head = col0 >> 6;  // col0 in 0..1023 here; tile within one head
  const int bb = row0 >> 11;
  const int t0 = row0 & 2047;
  unsigned short* dst = vbuf + (size_t)(bb * NH + head) * SEQ_T * DH;
  const int r4 = (lane >> 4) << 2;  // C row base (verified bf16 C layout)
#pragma unroll
  for (int m = 0; m < 2; ++m)
#pragma unroll
    for (int n = 0; n < 2; ++n)
#pragma unroll
      for (int j = 0; j < 4; ++j) {
        const int t = t0 + wr + 16 * m + r4 + j;
        const int d = wc + 16 * n + li;
        dst[(size_t)t * DH + d] = (unsigned short)f2bs(acc[m][n][j]);
      }
}

// Attention, MFMA candidate-filter scheme. Round-5 passing logic; this
// round adds register-prefetch of the next K-tile in both passes (16 VGPRs)
// so the ~300cy L2 staging latency hides under the gt/MFMA loop. Staged
// bytes and all arithmetic order unchanged — bit-identical output.
__global__ __launch_bounds__(256) void attn_topk(
    const float* __restrict__ q, const float* __restrict__ kmat,
    const unsigned short* __restrict__ kbf,
    const unsigned short* __restrict__ v, unsigned short* __restrict__ ctx) {
  __shared__ __align__(16) unsigned short kt[128 * 64];  // 16KB swizzled tile
  __shared__ double cs64[64][CAP];                       // 16KB exact scores
  __shared__ short ckey[64][CAP];                        // 4KB candidate keys
  __shared__ int ccnt[64];
  __shared__ double rthr[64];
  __shared__ float rmx[64];

  const int tid = threadIdx.x;
  const int lane = tid & 63;
  const int w = tid >> 6;
  const int bh = blockIdx.x & 31;
  const int t0 = (blockIdx.x >> 5) << 6;
  const size_t kbase = (size_t)bh * SEQ_T * DH;
  const int wrow0 = t0 + (w << 4);
  const int kA = (lane >> 4) << 3;                 // A/B-frag k-run offset
  const int rbase = wrow0 + ((lane >> 4) << 2);    // C row of acc[0]

  // Q fragment (A operand): row = lane&15, k = 8*(lane>>4)+j (+32 for half 1)
  bf16x8v qa0, qa1;
  {
    const float* qr = q + kbase + (size_t)(wrow0 + (lane & 15)) * DH;
    const float4 x0 = *(const float4*)(qr + kA);
    const float4 x1 = *(const float4*)(qr + kA + 4);
    const float4 y0 = *(const float4*)(qr + 32 + kA);
    const float4 y1 = *(const float4*)(qr + 32 + kA + 4);
    qa0[0] = f2bs(x0.x); qa0[1] = f2bs(x0.y);
    qa0[2] = f2bs(x0.z); qa0[3] = f2bs(x0.w);
    qa0[4] = f2bs(x1.x); qa0[5] = f2bs(x1.y);
    qa0[6] = f2bs(x1.z); qa0[7] = f2bs(x1.w);
    qa1[0] = f2bs(y0.x); qa1[1] = f2bs(y0.y);
    qa1[2] = f2bs(y0.z); qa1[3] = f2bs(y0.w);
    qa1[4] = f2bs(y1.x); qa1[5] = f2bs(y1.y);
    qa1[6] = f2bs(y1.z); qa1[7] = f2bs(y1.w);
  }

  const uint4* ksrc = (const uint4*)(kbf + ((size_t)bh << 17));
  const int nt = (t0 >> 7) + 1;       // tiles covering keys 0..t0+63
  const int wmax = wrow0 + 15;

  float tq[4][8];
#pragma unroll
  for (int j = 0; j < 4; ++j)
#pragma unroll
    for (int m = 0; m < 8; ++m) tq[j][m] = -FLT_MAX;

  uint4 pf[4];
#pragma unroll
  for (int i = 0; i < 4; ++i) pf[i] = ksrc[i * 256 + tid];

  // ---- pass 1: MFMA scores + per-lane top-8 per slot ----
  for (int T = 0; T < nt; ++T) {
    if (T) __syncthreads();
    {
      uint4* dv = (uint4*)kt;
#pragma unroll
      for (int i = 0; i < 4; ++i) dv[i * 256 + tid] = pf[i];
    }
    __syncthreads();
    if (T + 1 < nt) {
      const uint4* st = ksrc + (size_t)(T + 1) * 1024;
#pragma unroll
      for (int i = 0; i < 4; ++i) pf[i] = st[i * 256 + tid];
    }
    const int glim0 = (wmax - (T << 7)) >> 4;
    const int glim = glim0 > 7 ? 7 : glim0;
    for (int gt = 0; gt <= glim; ++gt) {
      const int kk = (gt << 4) + (lane & 15);
      const int key = (T << 7) + kk;
      const int b0 = ((kk << 7) | (kA << 1)) ^ ((kk & 7) << 4);
      const int b1 = ((kk << 7) | ((32 + kA) << 1)) ^ ((kk & 7) << 4);
      const bf16x8v kb0 = *(const bf16x8v*)((const char*)kt + b0);
      const bf16x8v kb1 = *(const bf16x8v*)((const char*)kt + b1);
      f32x4v acc = {0.f, 0.f, 0.f, 0.f};
      acc = __builtin_amdgcn_mfma_f32_16x16x32_bf16(qa0, kb0, acc, 0, 0, 0);
      acc = __builtin_amdgcn_mfma_f32_16x16x32_bf16(qa1, kb1, acc, 0, 0, 0);
#pragma unroll
      for (int j = 0; j < 4; ++j) {
        float sc = acc[j] * 0.125f;
        sc = (key <= rbase + j) ? sc : -FLT_MAX;
        if (sc > tq[j][7]) {
          float s = sc;
#pragma unroll
          for (int m = 0; m < 8; ++m) {
            const float hi = fmaxf(tq[j][m], s);
            s = fminf(tq[j][m], s);
            tq[j][m] = hi;
          }
        }
      }
    }
  }

  // ---- merge per slot across the 16-lane group (4 bitonic rounds) ----
#pragma unroll
  for (int j = 0; j < 4; ++j) {
#pragma unroll
    for (int xm = 1; xm < 16; xm <<= 1) {
      float m[8];
#pragma unroll
      for (int i = 0; i < 8; ++i) {
        const float pb = __shfl_xor(tq[j][7 - i], xm);
        m[i] = fmaxf(tq[j][i], pb);
      }
#pragma unroll
      for (int d = 4; d >= 1; d >>= 1)
#pragma unroll
        for (int i = 0; i < 8; ++i)
          if ((i & d) == 0 && (i | d) < 8) {
            const float hi = fmaxf(m[i], m[i | d]);
            const float lo = fminf(m[i], m[i | d]);
            m[i] = hi;
            m[i | d] = lo;
          }
#pragma unroll
      for (int i = 0; i < 8; ++i) tq[j][i] = m[i];
    }
  }
  float thrj[4];
#pragma unroll
  for (int j = 0; j < 4; ++j) {
    const int kf = (rbase + j + 1 < KSEL) ? (rbase + j + 1) : KSEL;
    float th = tq[j][7];
#pragma unroll
    for (int m = 0; m < 8; ++m)
      if (m == kf - 1) th = tq[j][m];
    thrj[j] = th - MFMA_MARGIN;
  }

  if (tid < 64) ccnt[tid] = 0;
  __syncthreads();

  // ---- pass 2: identical MFMA re-scan, collect candidates ----
#pragma unroll
  for (int i = 0; i < 4; ++i) pf[i] = ksrc[i * 256 + tid];
  for (int T = 0; T < nt; ++T) {
    if (T) __syncthreads();
    {
      uint4* dv = (uint4*)kt;
#pragma unroll
      for (int i = 0; i < 4; ++i) dv[i * 256 + tid] = pf[i];
    }
    __syncthreads();
    if (T + 1 < nt) {
      const uint4* st = ksrc + (size_t)(T + 1) * 1024;
#pragma unroll
      for (int i = 0; i < 4; ++i) pf[i] = st[i * 256 + tid];
    }
    const int glim0 = (wmax - (T << 7)) >> 4;
    const int glim = glim0 > 7 ? 7 : glim0;
    for (int gt = 0; gt <= glim; ++gt) {
      const int kk = (gt << 4) + (lane & 15);
      const int key = (T << 7) + kk;
      const int b0 = ((kk << 7) | (kA << 1)) ^ ((kk & 7) << 4);
      const int b1 = ((kk << 7) | ((32 + kA) << 1)) ^ ((kk & 7) << 4);
      const bf16x8v kb0 = *(const bf16x8v*)((const char*)kt + b0);
      const bf16x8v kb1 = *(const bf16x8v*)((const char*)kt + b1);
      f32x4v acc = {0.f, 0.f, 0.f, 0.f};
      acc = __builtin_amdgcn_mfma_f32_16x16x32_bf16(qa0, kb0, acc, 0, 0, 0);
      acc = __builtin_amdgcn_mfma_f32_16x16x32_bf16(qa1, kb1, acc, 0, 0, 0);
#pragma unroll
      for (int j = 0; j < 4; ++j) {
        const float sc = acc[j] * 0.125f;
        if (key <= rbase + j && sc >= thrj[j]) {
          const int rl = (w << 4) + ((lane >> 4) << 2) + j;
          const int p = atomicAdd(&ccnt[rl], 1);
          if (p < CAP) ckey[rl][p] = (short)key;
        }
      }
    }
  }

  // ---- phase 3A: exact fp64 rescore, lane-per-candidate, 2 rows/iter ----
  const int lid = lane & 31;
  for (int rp = 0; rp < 8; ++rp) {
    const int rl = (w << 4) + (rp << 1) + (lane >> 5);
    const int ncc = ccnt[rl] < CAP ? ccnt[rl] : CAP;
    if (lid < ncc) {
      const int key = ckey[rl][lid];
      const float* qr = q + kbase + (size_t)(t0 + rl) * DH;
      const float* kr = kmat + kbase + (size_t)key * DH;
      double s = 0.0;
#pragma unroll
      for (int d4 = 0; d4 < 16; ++d4) {
        const float4 qq = *(const float4*)(qr + (d4 << 2));
        const float4 kq = *(const float4*)(kr + (d4 << 2));
        s = fma((double)qq.x, (double)kq.x, s);
        s = fma((double)qq.y, (double)kq.y, s);
        s = fma((double)qq.z, (double)kq.z, s);
        s = fma((double)qq.w, (double)kq.w, s);
      }
      cs64[rl][lid] = s * 0.125;
    }
  }
  __syncthreads();

  // ---- phase 3B: per-row fp64 top-8 + threshold (row per lane) ----
  if (lane < 16) {
    const int rl = (w << 4) + lane;
    const int trow = t0 + rl;
    const int ncc = ccnt[rl] < CAP ? ccnt[rl] : CAP;
    double a64[8];
#pragma unroll
    for (int j = 0; j < 8; ++j) a64[j] = -DBL_MAX;
    for (int l = 0; l < ncc; ++l) {
      double sv = cs64[rl][l];
#pragma unroll
      for (int j = 0; j < 8; ++j) {
        const double hi = fmax(a64[j], sv);
        sv = fmin(a64[j], sv);
        a64[j] = hi;
      }
    }
    const int kf = (trow + 1 < KSEL) ? (trow + 1) : KSEL;
    double th = a64[7];
#pragma unroll
    for (int j = 0; j < 8; ++j)
      if (j == kf - 1) th = a64[j];
    rthr[rl] = th;
    rmx[rl] = (float)a64[0];
  }
  __syncthreads();

  // ---- phase 3C: sparse softmax * V, 4 interleaved row-chains ----
  for (int rg = 0; rg < 4; ++rg) {
    const int rlb = (w << 4) + (rg << 2);
    float acv[4] = {0.f, 0.f, 0.f, 0.f};
    float Zs[4] = {0.f, 0.f, 0.f, 0.f};
    int ncs[4];
    double ths[4];
    float mxs[4];
#pragma unroll
    for (int j = 0; j < 4; ++j) {
      const int rl = rlb + j;
      ncs[j] = ccnt[rl] < CAP ? ccnt[rl] : CAP;
      ths[j] = rthr[rl];
      mxs[j] = rmx[rl];
    }
    int nmax = ncs[0];
#pragma unroll
    for (int j = 1; j < 4; ++j) nmax = ncs[j] > nmax ? ncs[j] : nmax;
    for (int l = 0; l < nmax; ++l) {
#pragma unroll
      for (int j = 0; j < 4; ++j) {
        const int rl = rlb + j;
        if (l < ncs[j]) {
          const double s = cs64[rl][l];
          const float wgl = (s >= ths[j]) ? expf((float)s - mxs[j]) : 0.f;
          Zs[j] += wgl;
          acv[j] = fmaf(
              wgl,
              bf2f((unsigned int)v[kbase + (size_t)ckey[rl][l] * DH + lane]),
              acv[j]);
        }
      }
    }
#pragma unroll
    for (int j = 0; j < 4; ++j) {
      const int trow = t0 + rlb + j;
      __hip_bfloat16 h = __float2bfloat16(acv[j] / Zs[j]);
      ctx[((size_t)(bh >> 4) * SEQ_T + trow) * DIM_D + (bh & 15) * DH + lane] =
          *(unsigned short*)&h;
    }
  }
}

// Output projection via MFMA: A = ctx (exactly bf16), B = wout split to
// hi+lo bf16; C = A*Bh + A*Bl in fp32 accumulators (~1.6e-5 rel error vs
// fp32 chain — output threshold is 0.0765).
__global__ __launch_bounds__(256) void gemm_out(
    const unsigned short* __restrict__ A, const float* __restrict__ Bm,
    float* __restrict__ obuf) {
  __shared__ __align__(16) unsigned short Ah[64][40];
  __shared__ __align__(16) unsigned short Bh[64][40];
  __shared__ __align__(16) unsigned short Bl[64][40];
  const int tid = threadIdx.x;
  const int lane = tid & 63;
  const int w = tid >> 6;
  const int row0 = blockIdx.y * 64;
  const int col0 = blockIdx.x * 64;
  const int lrow = tid >> 2;
  const int lk = (tid & 3) << 3;
  const unsigned short* ap = A + (size_t)(row0 + lrow) * KDIM + lk;
  const float* bp = Bm + (size_t)(col0 + lrow) * KDIM + lk;
  const int wr = (w >> 1) << 5;
  const int wc = (w & 1) << 5;
  const int li = lane & 15;
  const int kA = (lane >> 4) << 3;

  f32x4v acc[2][2];
#pragma unroll
  for (int m = 0; m < 2; ++m)
#pragma unroll
    for (int n = 0; n < 2; ++n)
      acc[m][n] = (f32x4v){0.f, 0.f, 0.f, 0.f};

  uint4 ua = *(const uint4*)(ap);
  float4 rb0 = *(const float4*)(bp);
  float4 rb1 = *(const float4*)(bp + 4);
  for (int k0 = 0; k0 < KDIM; k0 += 32) {
    __syncthreads();
    *(uint4*)&Ah[lrow][lk] = ua;
    split8(rb0, rb1, &Bh[lrow][lk], &Bl[lrow][lk]);
    if (k0 + 32 < KDIM) {
      ua = *(const uint4*)(ap + k0 + 32);
      rb0 = *(const float4*)(bp + k0 + 32);
      rb1 = *(const float4*)(bp + k0 + 36);
    }
    __syncthreads();
    bf16x8v ah[2], bh[2], bl[2];
#pragma unroll
    for (int m = 0; m < 2; ++m) {
      ah[m] = *(const bf16x8v*)&Ah[wr + 16 * m + li][kA];
      bh[m] = *(const bf16x8v*)&Bh[wc + 16 * m + li][kA];
      bl[m] = *(const bf16x8v*)&Bl[wc + 16 * m + li][kA];
    }
#pragma unroll
    for (int m = 0; m < 2; ++m)
#pragma unroll
      for (int n = 0; n < 2; ++n) {
        acc[m][n] = __builtin_amdgcn_mfma_f32_16x16x32_bf16(ah[m], bh[n], acc[m][n], 0, 0, 0);
        acc[m][n] = __builtin_amdgcn_mfma_f32_16x16x32_bf16(ah[m], bl[n], acc[m][n], 0, 0, 0);
      }
  }

  const int r4 = (lane >> 4) << 2;
#pragma unroll
  for (int m = 0; m < 2; ++m)
#pragma unroll
    for (int n = 0; n < 2; ++n)
#pragma unroll
      for (int j = 0; j < 4; ++j) {
        const int r = row0 + wr + 16 * m + r4 + j;
        const int c = col0 + wc + 16 * n + li;
        obuf[(size_t)r * DIM_D + c] = acc[m][n][j];
      }
}

extern "C" void kernel_launch(void* const* d_in, const int* in_sizes, int n_in,
                              void* d_out, int out_size, void* d_ws,
                              size_t ws_size, hipStream_t stream) {
  (void)out_size; (void)ws_size;
  const float* x = (const float*)d_in[0];
  const float* wqkv = (const float*)d_in[1];
  const float* wout = (const float*)d_in[2];
  for (int i = 0; i < n_in; ++i) {
    if (in_sizes[i] == NUM_B * SEQ_T * DIM_D) x = (const float*)d_in[i];
    else if (in_sizes[i] == 3 * DIM_D * DIM_D) wqkv = (const float*)d_in[i];
    else if (in_sizes[i] == DIM_D * DIM_D) wout = (const float*)d_in[i];
  }
  float* out = (float*)d_out;

  const size_t qkv_elems = (size_t)NUM_B * NH * SEQ_T * DH;   // 4.19M
  float* qbuf = (float*)d_ws;
  float* kbuf = qbuf + qkv_elems;
  unsigned short* vbuf = (unsigned short*)(kbuf + qkv_elems);
  unsigned short* ctxb = vbuf + qkv_elems;
  unsigned short* kbf = ctxb + (size_t)NUM_B * SEQ_T * DIM_D;  // bf16 K tiles

  gemm_qk<<<dim3(2 * DIM_D / 64, NUM_B * SEQ_T / 64), 256, 0, stream>>>(
      x, wqkv, qbuf, kbuf, kbf);
  gemm_v<<<dim3(DIM_D / 64, NUM_B * SEQ_T / 64), 256, 0, stream>>>(
      x, wqkv + (size_t)2 * DIM_D * KDIM, vbuf);
  attn_topk<<<dim3(NUM_B * NH * (SEQ_T / 64)), 256, 0, stream>>>(
      qbuf, kbuf, kbf, vbuf, ctxb);
  gemm_out<<<dim3(DIM_D / 64, NUM_B * SEQ_T / 64), 256, 0, stream>>>(
      ctxb, wout, out);
}

// Round 8
// 609.613 us; speedup vs baseline: 1.2365x; 1.1008x over previous
//
#include <hip/hip_runtime.h>
#include <hip/hip_bf16.h>
#include <math.h>
#include <float.h>

#define NUM_B 2
#define SEQ_T 2048
#define DIM_D 1024
#define NH 16
#define DH 64
#define KDIM 1024
#define KSEL 8

// attention candidate scheme
#define CAP 32
#define MFMA_MARGIN 0.06f

typedef __attribute__((ext_vector_type(8))) short bf16x8v;   // 8 bf16 (4 VGPR)
typedef __attribute__((ext_vector_type(4))) float f32x4v;    // MFMA acc
typedef __attribute__((ext_vector_type(4))) double f64x4v;   // f64 MFMA acc

__device__ __forceinline__ float bf2f(unsigned int u) {
  union { unsigned int i; float f; } v; v.i = u << 16; return v.f;
}

__device__ __forceinline__ short f2bs(float f) {
  __hip_bfloat16 h = __float2bfloat16(f);
  return *(short*)&h;
}

// split x into hi+lo bf16 (residual ~1.6e-5 rel); store 8 to LDS as 16B each
__device__ __forceinline__ void split8(float4 x0, float4 x1,
                                       unsigned short* __restrict__ hp,
                                       unsigned short* __restrict__ lp) {
  unsigned short h[8], l[8];
  const float xs[8] = {x0.x, x0.y, x0.z, x0.w, x1.x, x1.y, x1.z, x1.w};
#pragma unroll
  for (int j = 0; j < 8; ++j) {
    const short hb = f2bs(xs[j]);
    h[j] = (unsigned short)hb;
    const float hf = bf2f((unsigned int)(unsigned short)hb);
    l[j] = (unsigned short)f2bs(xs[j] - hf);
  }
  *(uint4*)hp = *(const uint4*)h;
  *(uint4*)lp = *(const uint4*)l;
}

// Q,K projection (cols 0..2047 of qkv): fp64 accumulation via
// v_mfma_f64_16x16x4. Per-wave k-order ascending 0..1023 in 4-k steps,
// same instruction/fragments as rounds 3-7 — BIT-IDENTICAL Q/K
// (selection-critical).
// Round-7 lesson: barrier COUNT isn't the limiter (3 schedules all ~316us,
// MfmaUtil 75%). This round: 512-thread blocks, 64x128 tile (8 waves 2x4),
// LDS 27.6KB -> 4 blocks/CU = 2x wave residency, 2x B-panel reuse — feed
// the 64-cyc-issue f64 pipe from more independent waves.
// C/D layout decoded at runtime with probe MFMAs (round-2 lesson).
// Also emits kbf: bf16 K image, XOR-swizzled for attn's linear staging.
__global__ __launch_bounds__(512) void gemm_qk(
    const float* __restrict__ A, const float* __restrict__ Bm,
    float* __restrict__ qbuf, float* __restrict__ kbuf,
    unsigned short* __restrict__ kbf) {
  __shared__ __align__(16) float As[64][36];    // row-major, +4 pad
  __shared__ __align__(16) float Bs[128][36];
  const int tid = threadIdx.x;
  const int lane = tid & 63;
  const int w = tid >> 6;           // 0..7
  const int row0 = blockIdx.y * 64;
  const int col0 = blockIdx.x * 128;
  // A staging: 64 rows x 32k, 4 floats/thread
  const int lrA = tid >> 3;         // 0..63
  const int lkA = (tid & 7) << 2;   // 0..28 step 4
  // B staging: 128 rows x 32k, 8 floats/thread
  const int lrB = tid >> 2;         // 0..127
  const int lkB = (tid & 3) << 3;   // 0,8,16,24
  const float* ap = A + (size_t)(row0 + lrA) * KDIM + lkA;
  const float* bp = Bm + (size_t)(col0 + lrB) * KDIM + lkB;
  const int wr = (w >> 2) << 5;     // 0 or 32
  const int wc = (w & 3) << 5;      // 0,32,64,96
  const int li = lane & 15;
  const int lk4 = lane >> 4;

  // ---- C/D layout probe: decode (row,col) of each acc slot at runtime ----
  int rowof[4], colof[4];
  {
    f64x4v pr = {0.0, 0.0, 0.0, 0.0};
    f64x4v pc = {0.0, 0.0, 0.0, 0.0};
    const double vidx = (double)li;
    pr = __builtin_amdgcn_mfma_f64_16x16x4f64(vidx, 1.0, pr, 0, 0, 0);
    pc = __builtin_amdgcn_mfma_f64_16x16x4f64(1.0, vidx, pc, 0, 0, 0);
#pragma unroll
    for (int vj = 0; vj < 4; ++vj) {
      rowof[vj] = (int)(pr[vj] * 0.25 + 0.5);
      colof[vj] = (int)(pc[vj] * 0.25 + 0.5);
    }
  }

  f64x4v acc[2][2];
#pragma unroll
  for (int m = 0; m < 2; ++m)
#pragma unroll
    for (int n = 0; n < 2; ++n)
      acc[m][n] = (f64x4v){0.0, 0.0, 0.0, 0.0};

  // register prefetch one chunk ahead (3 float4 = 12 VGPR, spill-safe)
  float4 ra = *(const float4*)(ap);
  float4 rb0 = *(const float4*)(bp);
  float4 rb1 = *(const float4*)(bp + 4);
  for (int k0 = 0; k0 < KDIM; k0 += 32) {
    __syncthreads();   // previous chunk's readers done
    *(float4*)&As[lrA][lkA] = ra;
    *(float4*)&Bs[lrB][lkB] = rb0;
    *(float4*)&Bs[lrB][lkB + 4] = rb1;
    if (k0 + 32 < KDIM) {
      ra = *(const float4*)(ap + k0 + 32);
      rb0 = *(const float4*)(bp + k0 + 32);
      rb1 = *(const float4*)(bp + k0 + 36);
    }
    __syncthreads();
#pragma unroll
    for (int ks = 0; ks < 32; ks += 4) {
      const int kk = ks + lk4;
      const double af0 = (double)As[wr + li][kk];
      const double af1 = (double)As[wr + 16 + li][kk];
      const double bf0 = (double)Bs[wc + li][kk];
      const double bf1 = (double)Bs[wc + 16 + li][kk];
      acc[0][0] = __builtin_amdgcn_mfma_f64_16x16x4f64(af0, bf0, acc[0][0], 0, 0, 0);
      acc[0][1] = __builtin_amdgcn_mfma_f64_16x16x4f64(af0, bf1, acc[0][1], 0, 0, 0);
      acc[1][0] = __builtin_amdgcn_mfma_f64_16x16x4f64(af1, bf0, acc[1][0], 0, 0, 0);
      acc[1][1] = __builtin_amdgcn_mfma_f64_16x16x4f64(af1, bf1, acc[1][1], 0, 0, 0);
    }
  }

  const int bb = row0 >> 11;
  const int t0 = row0 & 2047;
#pragma unroll
  for (int m = 0; m < 2; ++m)
#pragma unroll
    for (int n = 0; n < 2; ++n)
#pragma unroll
      for (int vj = 0; vj < 4; ++vj) {
        const int r = wr + 16 * m + rowof[vj];         // row in tile (0..63)
        const int gc = col0 + wc + 16 * n + colof[vj]; // global qkv col
        const int qi = gc >> 10;                       // 0=q 1=k (blk-uniform)
        const int head = (gc & 1023) >> 6;
        const int d = gc & 63;
        const int t = t0 + r;
        const float fv = (float)acc[m][n][vj];
        float* dst = ((qi == 0) ? qbuf : kbuf) +
                     (size_t)(bb * NH + head) * SEQ_T * DH;
        dst[(size_t)t * DH + d] = fv;
        if (qi == 1) {
          unsigned short* kb = kbf + ((size_t)(bb * NH + head) << 17);
          const int key = t & 127;
          const int off =
              (((t >> 7) << 13) | (key << 6) | d) ^ ((key & 7) << 3);
          __hip_bfloat16 hb = __float2bfloat16(fv);
          kb[off] = *(unsigned short*)&hb;
        }
      }
}

// V projection (cols 2048..3071): split-bf16 MFMA (round-4 passing version).
// C = Ah*Bh + Ah*Bl + Al*Bh; dropped lo*lo ~1.6e-5 rel, invisible at V's
// bf16 granularity. Bm passed pre-offset to wqkv + 2048*KDIM.
__global__ __launch_bounds__(256) void gemm_v(
    const float* __restrict__ A, const float* __restrict__ Bm,
    unsigned short* __restrict__ vbuf) {
  __shared__ __align__(16) unsigned short Ah[64][40];  // rows padded to 80B
  __shared__ __align__(16) unsigned short Al[64][40];
  __shared__ __align__(16) unsigned short Bh[64][40];
  __shared__ __align__(16) unsigned short Bl[64][40];
  const int tid = threadIdx.x;
  const int lane = tid & 63;
  const int w = tid >> 6;
  const int row0 = blockIdx.y * 64;
  const int col0 = blockIdx.x * 64;
  const int lrow = tid >> 2;
  const int lk = (tid & 3) << 3;
  const float* ap = A + (size_t)(row0 + lrow) * KDIM + lk;
  const float* bp = Bm + (size_t)(col0 + lrow) * KDIM + lk;
  const int wr = (w >> 1) << 5;
  const int wc = (w & 1) << 5;
  const int li = lane & 15;
  const int kA = (lane >> 4) << 3;   // frag k-run: k = kA + j (verified map)

  f32x4v acc[2][2];
#pragma unroll
  for (int m = 0; m < 2; ++m)
#pragma unroll
    for (int n = 0; n < 2; ++n)
      acc[m][n] = (f32x4v){0.f, 0.f, 0.f, 0.f};

  float4 ra0 = *(const float4*)(ap);
  float4 ra1 = *(const float4*)(ap + 4);
  float4 rb0 = *(const float4*)(bp);
  float4 rb1 = *(const float4*)(bp + 4);
  for (int k0 = 0; k0 < KDIM; k0 += 32) {
    __syncthreads();
    split8(ra0, ra1, &Ah[lrow][lk], &Al[lrow][lk]);
    split8(rb0, rb1, &Bh[lrow][lk], &Bl[lrow][lk]);
    if (k0 + 32 < KDIM) {
      ra0 = *(const float4*)(ap + k0 + 32);
      ra1 = *(const float4*)(ap + k0 + 36);
      rb0 = *(const float4*)(bp + k0 + 32);
      rb1 = *(const float4*)(bp + k0 + 36);
    }
    __syncthreads();
    bf16x8v ah[2], al[2], bh[2], bl[2];
#pragma unroll
    for (int m = 0; m < 2; ++m) {
      ah[m] = *(const bf16x8v*)&Ah[wr + 16 * m + li][kA];
      al[m] = *(const bf16x8v*)&Al[wr + 16 * m + li][kA];
      bh[m] = *(const bf16x8v*)&Bh[wc + 16 * m + li][kA];
      bl[m] = *(const bf16x8v*)&Bl[wc + 16 * m + li][kA];
    }
#pragma unroll
    for (int m = 0; m < 2; ++m)
#pragma unroll
      for (int n = 0; n < 2; ++n) {
        acc[m][n] = __builtin_amdgcn_mfma_f32_16x16x32_bf16(ah[m], bh[n], acc[m][n], 0, 0, 0);
        acc[m][n] = __builtin_amdgcn_mfma_f32_16x16x32_bf16(ah[m], bl[n], acc[m][n], 0, 0, 0);
        acc[m][n] = __builtin_amdgcn_mfma_f32_16x16x32_bf16(al[m], bh[n], acc[m][n], 0, 0, 0);
      }
  }

  const int head = col0 >> 6;  // col0 in 0..1023 here; tile within one head
  const int bb = row0 >> 11;
  const int t0 = row0 & 2047;
  unsigned short* dst = vbuf + (size_t)(bb * NH + head) * SEQ_T * DH;
  const int r4 = (lane >> 4) << 2;  // C row base (verified bf16 C layout)
#pragma unroll
  for (int m = 0; m < 2; ++m)
#pragma unroll
    for (int n = 0; n < 2; ++n)
#pragma unroll
      for (int j = 0; j < 4; ++j) {
        const int t = t0 + wr + 16 * m + r4 + j;
        const int d = wc + 16 * n + li;
        dst[(size_t)t * DH + d] = (unsigned short)f2bs(acc[m][n][j]);
      }
}

// Attention, MFMA candidate-filter scheme — round-5 passing version
// (round-7's K-tile register prefetch REVERTED: it cost ~46us, likely VGPR
// pressure; this is the exact round-5 code).
__global__ __launch_bounds__(256) void attn_topk(
    const float* __restrict__ q, const float* __restrict__ kmat,
    const unsigned short* __restrict__ kbf,
    const unsigned short* __restrict__ v, unsigned short* __restrict__ ctx) {
  __shared__ __align__(16) unsigned short kt[128 * 64];  // 16KB swizzled tile
  __shared__ double cs64[64][CAP];                       // 16KB exact scores
  __shared__ short ckey[64][CAP];                        // 4KB candidate keys
  __shared__ int ccnt[64];
  __shared__ double rthr[64];
  __shared__ float rmx[64];

  const int tid = threadIdx.x;
  const int lane = tid & 63;
  const int w = tid >> 6;
  const int bh = blockIdx.x & 31;
  const int t0 = (blockIdx.x >> 5) << 6;
  const size_t kbase = (size_t)bh * SEQ_T * DH;
  const int wrow0 = t0 + (w << 4);
  const int kA = (lane >> 4) << 3;                 // A/B-frag k-run offset
  const int rbase = wrow0 + ((lane >> 4) << 2);    // C row of acc[0]

  // Q fragment (A operand): row = lane&15, k = 8*(lane>>4)+j (+32 for half 1)
  bf16x8v qa0, qa1;
  {
    const float* qr = q + kbase + (size_t)(wrow0 + (lane & 15)) * DH;
    const float4 x0 = *(const float4*)(qr + kA);
    const float4 x1 = *(const float4*)(qr + kA + 4);
    const float4 y0 = *(const float4*)(qr + 32 + kA);
    const float4 y1 = *(const float4*)(qr + 32 + kA + 4);
    qa0[0] = f2bs(x0.x); qa0[1] = f2bs(x0.y);
    qa0[2] = f2bs(x0.z); qa0[3] = f2bs(x0.w);
    qa0[4] = f2bs(x1.x); qa0[5] = f2bs(x1.y);
    qa0[6] = f2bs(x1.z); qa0[7] = f2bs(x1.w);
    qa1[0] = f2bs(y0.x); qa1[1] = f2bs(y0.y);
    qa1[2] = f2bs(y0.z); qa1[3] = f2bs(y0.w);
    qa1[4] = f2bs(y1.x); qa1[5] = f2bs(y1.y);
    qa1[6] = f2bs(y1.z); qa1[7] = f2bs(y1.w);
  }

  const uint4* ksrc = (const uint4*)(kbf + ((size_t)bh << 17));
  const int nt = (t0 >> 7) + 1;       // tiles covering keys 0..t0+63
  const int wmax = wrow0 + 15;

  float tq[4][8];
#pragma unroll
  for (int j = 0; j < 4; ++j)
#pragma unroll
    for (int m = 0; m < 8; ++m) tq[j][m] = -FLT_MAX;

  // ---- pass 1: MFMA scores + per-lane top-8 per slot ----
  for (int T = 0; T < nt; ++T) {
    if (T) __syncthreads();
    {
      const uint4* st = ksrc + (size_t)T * 1024;
      uint4* dv = (uint4*)kt;
#pragma unroll
      for (int i = 0; i < 4; ++i) dv[i * 256 + tid] = st[i * 256 + tid];
    }
    __syncthreads();
    const int glim0 = (wmax - (T << 7)) >> 4;
    const int glim = glim0 > 7 ? 7 : glim0;
    for (int gt = 0; gt <= glim; ++gt) {
      const int kk = (gt << 4) + (lane & 15);
      const int key = (T << 7) + kk;
      const int b0 = ((kk << 7) | (kA << 1)) ^ ((kk & 7) << 4);
      const int b1 = ((kk << 7) | ((32 + kA) << 1)) ^ ((kk & 7) << 4);
      const bf16x8v kb0 = *(const bf16x8v*)((const char*)kt + b0);
      const bf16x8v kb1 = *(const bf16x8v*)((const char*)kt + b1);
      f32x4v acc = {0.f, 0.f, 0.f, 0.f};
      acc = __builtin_amdgcn_mfma_f32_16x16x32_bf16(qa0, kb0, acc, 0, 0, 0);
      acc = __builtin_amdgcn_mfma_f32_16x16x32_bf16(qa1, kb1, acc, 0, 0, 0);
#pragma unroll
      for (int j = 0; j < 4; ++j) {
        float sc = acc[j] * 0.125f;
        sc = (key <= rbase + j) ? sc : -FLT_MAX;
        if (sc > tq[j][7]) {
          float s = sc;
#pragma unroll
          for (int m = 0; m < 8; ++m) {
            const float hi = fmaxf(tq[j][m], s);
            s = fminf(tq[j][m], s);
            tq[j][m] = hi;
          }
        }
      }
    }
  }

  // ---- merge per slot across the 16-lane group (4 bitonic rounds) ----
#pragma unroll
  for (int j = 0; j < 4; ++j) {
#pragma unroll
    for (int xm = 1; xm < 16; xm <<= 1) {
      float m[8];
#pragma unroll
      for (int i = 0; i < 8; ++i) {
        const float pb = __shfl_xor(tq[j][7 - i], xm);
        m[i] = fmaxf(tq[j][i], pb);
      }
#pragma unroll
      for (int d = 4; d >= 1; d >>= 1)
#pragma unroll
        for (int i = 0; i < 8; ++i)
          if ((i & d) == 0 && (i | d) < 8) {
            const float hi = fmaxf(m[i], m[i | d]);
            const float lo = fminf(m[i], m[i | d]);
            m[i] = hi;
            m[i | d] = lo;
          }
#pragma unroll
      for (int i = 0; i < 8; ++i) tq[j][i] = m[i];
    }
  }
  float thrj[4];
#pragma unroll
  for (int j = 0; j < 4; ++j) {
    const int kf = (rbase + j + 1 < KSEL) ? (rbase + j + 1) : KSEL;
    float th = tq[j][7];
#pragma unroll
    for (int m = 0; m < 8; ++m)
      if (m == kf - 1) th = tq[j][m];
    thrj[j] = th - MFMA_MARGIN;
  }

  if (tid < 64) ccnt[tid] = 0;
  __syncthreads();

  // ---- pass 2: identical MFMA re-scan, collect candidates ----
  for (int T = 0; T < nt; ++T) {
    if (T) __syncthreads();
    {
      const uint4* st = ksrc + (size_t)T * 1024;
      uint4* dv = (uint4*)kt;
#pragma unroll
      for (int i = 0; i < 4; ++i) dv[i * 256 + tid] = st[i * 256 + tid];
    }
    __syncthreads();
    const int glim0 = (wmax - (T << 7)) >> 4;
    const int glim = glim0 > 7 ? 7 : glim0;
    for (int gt = 0; gt <= glim; ++gt) {
      const int kk = (gt << 4) + (lane & 15);
      const int key = (T << 7) + kk;
      const int b0 = ((kk << 7) | (kA << 1)) ^ ((kk & 7) << 4);
      const int b1 = ((kk << 7) | ((32 + kA) << 1)) ^ ((kk & 7) << 4);
      const bf16x8v kb0 = *(const bf16x8v*)((const char*)kt + b0);
      const bf16x8v kb1 = *(const bf16x8v*)((const char*)kt + b1);
      f32x4v acc = {0.f, 0.f, 0.f, 0.f};
      acc = __builtin_amdgcn_mfma_f32_16x16x32_bf16(qa0, kb0, acc, 0, 0, 0);
      acc = __builtin_amdgcn_mfma_f32_16x16x32_bf16(qa1, kb1, acc, 0, 0, 0);
#pragma unroll
      for (int j = 0; j < 4; ++j) {
        const float sc = acc[j] * 0.125f;
        if (key <= rbase + j && sc >= thrj[j]) {
          const int rl = (w << 4) + ((lane >> 4) << 2) + j;
          const int p = atomicAdd(&ccnt[rl], 1);
          if (p < CAP) ckey[rl][p] = (short)key;
        }
      }
    }
  }

  // ---- phase 3A: exact fp64 rescore, lane-per-candidate, 2 rows/iter ----
  const int lid = lane & 31;
  for (int rp = 0; rp < 8; ++rp) {
    const int rl = (w << 4) + (rp << 1) + (lane >> 5);
    const int ncc = ccnt[rl] < CAP ? ccnt[rl] : CAP;
    if (lid < ncc) {
      const int key = ckey[rl][lid];
      const float* qr = q + kbase + (size_t)(t0 + rl) * DH;
      const float* kr = kmat + kbase + (size_t)key * DH;
      double s = 0.0;
#pragma unroll
      for (int d4 = 0; d4 < 16; ++d4) {
        const float4 qq = *(const float4*)(qr + (d4 << 2));
        const float4 kq = *(const float4*)(kr + (d4 << 2));
        s = fma((double)qq.x, (double)kq.x, s);
        s = fma((double)qq.y, (double)kq.y, s);
        s = fma((double)qq.z, (double)kq.z, s);
        s = fma((double)qq.w, (double)kq.w, s);
      }
      cs64[rl][lid] = s * 0.125;
    }
  }
  __syncthreads();

  // ---- phase 3B: per-row fp64 top-8 + threshold (row per lane) ----
  if (lane < 16) {
    const int rl = (w << 4) + lane;
    const int trow = t0 + rl;
    const int ncc = ccnt[rl] < CAP ? ccnt[rl] : CAP;
    double a64[8];
#pragma unroll
    for (int j = 0; j < 8; ++j) a64[j] = -DBL_MAX;
    for (int l = 0; l < ncc; ++l) {
      double sv = cs64[rl][l];
#pragma unroll
      for (int j = 0; j < 8; ++j) {
        const double hi = fmax(a64[j], sv);
        sv = fmin(a64[j], sv);
        a64[j] = hi;
      }
    }
    const int kf = (trow + 1 < KSEL) ? (trow + 1) : KSEL;
    double th = a64[7];
#pragma unroll
    for (int j = 0; j < 8; ++j)
      if (j == kf - 1) th = a64[j];
    rthr[rl] = th;
    rmx[rl] = (float)a64[0];
  }
  __syncthreads();

  // ---- phase 3C: sparse softmax * V, 4 interleaved row-chains ----
  for (int rg = 0; rg < 4; ++rg) {
    const int rlb = (w << 4) + (rg << 2);
    float acv[4] = {0.f, 0.f, 0.f, 0.f};
    float Zs[4] = {0.f, 0.f, 0.f, 0.f};
    int ncs[4];
    double ths[4];
    float mxs[4];
#pragma unroll
    for (int j = 0; j < 4; ++j) {
      const int rl = rlb + j;
      ncs[j] = ccnt[rl] < CAP ? ccnt[rl] : CAP;
      ths[j] = rthr[rl];
      mxs[j] = rmx[rl];
    }
    int nmax = ncs[0];
#pragma unroll
    for (int j = 1; j < 4; ++j) nmax = ncs[j] > nmax ? ncs[j] : nmax;
    for (int l = 0; l < nmax; ++l) {
#pragma unroll
      for (int j = 0; j < 4; ++j) {
        const int rl = rlb + j;
        if (l < ncs[j]) {
          const double s = cs64[rl][l];
          const float wgl = (s >= ths[j]) ? expf((float)s - mxs[j]) : 0.f;
          Zs[j] += wgl;
          acv[j] = fmaf(
              wgl,
              bf2f((unsigned int)v[kbase + (size_t)ckey[rl][l] * DH + lane]),
              acv[j]);
        }
      }
    }
#pragma unroll
    for (int j = 0; j < 4; ++j) {
      const int trow = t0 + rlb + j;
      __hip_bfloat16 h = __float2bfloat16(acv[j] / Zs[j]);
      ctx[((size_t)(bh >> 4) * SEQ_T + trow) * DIM_D + (bh & 15) * DH + lane] =
          *(unsigned short*)&h;
    }
  }
}

// Output projection via MFMA: A = ctx (exactly bf16), B = wout split to
// hi+lo bf16; C = A*Bh + A*Bl in fp32 accumulators (~1.6e-5 rel error vs
// fp32 chain — output threshold is 0.0765).
__global__ __launch_bounds__(256) void gemm_out(
    const unsigned short* __restrict__ A, const float* __restrict__ Bm,
    float* __restrict__ obuf) {
  __shared__ __align__(16) unsigned short Ah[64][40];
  __shared__ __align__(16) unsigned short Bh[64][40];
  __shared__ __align__(16) unsigned short Bl[64][40];
  const int tid = threadIdx.x;
  const int lane = tid & 63;
  const int w = tid >> 6;
  const int row0 = blockIdx.y * 64;
  const int col0 = blockIdx.x * 64;
  const int lrow = tid >> 2;
  const int lk = (tid & 3) << 3;
  const unsigned short* ap = A + (size_t)(row0 + lrow) * KDIM + lk;
  const float* bp = Bm + (size_t)(col0 + lrow) * KDIM + lk;
  const int wr = (w >> 1) << 5;
  const int wc = (w & 1) << 5;
  const int li = lane & 15;
  const int kA = (lane >> 4) << 3;

  f32x4v acc[2][2];
#pragma unroll
  for (int m = 0; m < 2; ++m)
#pragma unroll
    for (int n = 0; n < 2; ++n)
      acc[m][n] = (f32x4v){0.f, 0.f, 0.f, 0.f};

  uint4 ua = *(const uint4*)(ap);
  float4 rb0 = *(const float4*)(bp);
  float4 rb1 = *(const float4*)(bp + 4);
  for (int k0 = 0; k0 < KDIM; k0 += 32) {
    __syncthreads();
    *(uint4*)&Ah[lrow][lk] = ua;
    split8(rb0, rb1, &Bh[lrow][lk], &Bl[lrow][lk]);
    if (k0 + 32 < KDIM) {
      ua = *(const uint4*)(ap + k0 + 32);
      rb0 = *(const float4*)(bp + k0 + 32);
      rb1 = *(const float4*)(bp + k0 + 36);
    }
    __syncthreads();
    bf16x8v ah[2], bh[2], bl[2];
#pragma unroll
    for (int m = 0; m < 2; ++m) {
      ah[m] = *(const bf16x8v*)&Ah[wr + 16 * m + li][kA];
      bh[m] = *(const bf16x8v*)&Bh[wc + 16 * m + li][kA];
      bl[m] = *(const bf16x8v*)&Bl[wc + 16 * m + li][kA];
    }
#pragma unroll
    for (int m = 0; m < 2; ++m)
#pragma unroll
      for (int n = 0; n < 2; ++n) {
        acc[m][n] = __builtin_amdgcn_mfma_f32_16x16x32_bf16(ah[m], bh[n], acc[m][n], 0, 0, 0);
        acc[m][n] = __builtin_amdgcn_mfma_f32_16x16x32_bf16(ah[m], bl[n], acc[m][n], 0, 0, 0);
      }
  }

  const int r4 = (lane >> 4) << 2;
#pragma unroll
  for (int m = 0; m < 2; ++m)
#pragma unroll
    for (int n = 0; n < 2; ++n)
#pragma unroll
      for (int j = 0; j < 4; ++j) {
        const int r = row0 + wr + 16 * m + r4 + j;
        const int c = col0 + wc + 16 * n + li;
        obuf[(size_t)r * DIM_D + c] = acc[m][n][j];
      }
}

extern "C" void kernel_launch(void* const* d_in, const int* in_sizes, int n_in,
                              void* d_out, int out_size, void* d_ws,
                              size_t ws_size, hipStream_t stream) {
  (void)out_size; (void)ws_size;
  const float* x = (const float*)d_in[0];
  const float* wqkv = (const float*)d_in[1];
  const float* wout = (const float*)d_in[2];
  for (int i = 0; i < n_in; ++i) {
    if (in_sizes[i] == NUM_B * SEQ_T * DIM_D) x = (const float*)d_in[i];
    else if (in_sizes[i] == 3 * DIM_D * DIM_D) wqkv = (const float*)d_in[i];
    else if (in_sizes[i] == DIM_D * DIM_D) wout = (const float*)d_in[i];
  }
  float* out = (float*)d_out;

  const size_t qkv_elems = (size_t)NUM_B * NH * SEQ_T * DH;   // 4.19M
  float* qbuf = (float*)d_ws;
  float* kbuf = qbuf + qkv_elems;
  unsigned short* vbuf = (unsigned short*)(kbuf + qkv_elems);
  unsigned short* ctxb = vbuf + qkv_elems;
  unsigned short* kbf = ctxb + (size_t)NUM_B * SEQ_T * DIM_D;  // bf16 K tiles

  gemm_qk<<<dim3(2 * DIM_D / 128, NUM_B * SEQ_T / 64), 512, 0, stream>>>(
      x, wqkv, qbuf, kbuf, kbf);
  gemm_v<<<dim3(DIM_D / 64, NUM_B * SEQ_T / 64), 256, 0, stream>>>(
      x, wqkv + (size_t)2 * DIM_D * KDIM, vbuf);
  attn_topk<<<dim3(NUM_B * NH * (SEQ_T / 64)), 256, 0, stream>>>(
      qbuf, kbuf, kbf, vbuf, ctxb);
  gemm_out<<<dim3(DIM_D / 64, NUM_B * SEQ_T / 64), 256, 0, stream>>>(
      ctxb, wout, out);
}

// Round 9
// 592.416 us; speedup vs baseline: 1.2724x; 1.0290x over previous
//
#include <hip/hip_runtime.h>
#include <hip/hip_bf16.h>
#include <math.h>
#include <float.h>

#define NUM_B 2
#define SEQ_T 2048
#define DIM_D 1024
#define NH 16
#define DH 64
#define KDIM 1024
#define KSEL 8

// attention candidate scheme
#define CAP 32
#define MFMA_MARGIN 0.06f

typedef __attribute__((ext_vector_type(8))) short bf16x8v;   // 8 bf16 (4 VGPR)
typedef __attribute__((ext_vector_type(4))) float f32x4v;    // MFMA acc
typedef __attribute__((ext_vector_type(4))) double f64x4v;   // f64 MFMA acc

__device__ __forceinline__ float bf2f(unsigned int u) {
  union { unsigned int i; float f; } v; v.i = u << 16; return v.f;
}

__device__ __forceinline__ short f2bs(float f) {
  __hip_bfloat16 h = __float2bfloat16(f);
  return *(short*)&h;
}

// split x into hi+lo bf16 (residual ~1.6e-5 rel); store 8 to LDS as 16B each
__device__ __forceinline__ void split8(float4 x0, float4 x1,
                                       unsigned short* __restrict__ hp,
                                       unsigned short* __restrict__ lp) {
  unsigned short h[8], l[8];
  const float xs[8] = {x0.x, x0.y, x0.z, x0.w, x1.x, x1.y, x1.z, x1.w};
#pragma unroll
  for (int j = 0; j < 8; ++j) {
    const short hb = f2bs(xs[j]);
    h[j] = (unsigned short)hb;
    const float hf = bf2f((unsigned int)(unsigned short)hb);
    l[j] = (unsigned short)f2bs(xs[j] - hf);
  }
  *(uint4*)hp = *(const uint4*)h;
  *(uint4*)lp = *(const uint4*)l;
}

// split 4 floats into hi+lo bf16; store as 8B each
__device__ __forceinline__ void split4(float4 x,
                                       unsigned short* __restrict__ hp,
                                       unsigned short* __restrict__ lp) {
  unsigned short h[4], l[4];
  const float xs[4] = {x.x, x.y, x.z, x.w};
#pragma unroll
  for (int j = 0; j < 4; ++j) {
    const short hb = f2bs(xs[j]);
    h[j] = (unsigned short)hb;
    const float hf = bf2f((unsigned int)(unsigned short)hb);
    l[j] = (unsigned short)f2bs(xs[j] - hf);
  }
  *(uint2*)hp = *(const uint2*)h;
  *(uint2*)lp = *(const uint2*)l;
}

// Q,K projection (cols 0..2047 of qkv): fp64 accumulation via
// v_mfma_f64_16x16x4. Per-wave k-order ascending 0..1023 in 4-k steps,
// same instruction/fragments as rounds 3-8 — BIT-IDENTICAL Q/K
// (selection-critical). Round-8 passing version: 512 threads, 64x128 tile
// (8 waves 2x4), MfmaUtil 80%.
// C/D layout decoded at runtime with probe MFMAs (round-2 lesson).
// Also emits kbf: bf16 K image, XOR-swizzled for attn's linear staging.
__global__ __launch_bounds__(512) void gemm_qk(
    const float* __restrict__ A, const float* __restrict__ Bm,
    float* __restrict__ qbuf, float* __restrict__ kbuf,
    unsigned short* __restrict__ kbf) {
  __shared__ __align__(16) float As[64][36];    // row-major, +4 pad
  __shared__ __align__(16) float Bs[128][36];
  const int tid = threadIdx.x;
  const int lane = tid & 63;
  const int w = tid >> 6;           // 0..7
  const int row0 = blockIdx.y * 64;
  const int col0 = blockIdx.x * 128;
  // A staging: 64 rows x 32k, 4 floats/thread
  const int lrA = tid >> 3;         // 0..63
  const int lkA = (tid & 7) << 2;   // 0..28 step 4
  // B staging: 128 rows x 32k, 8 floats/thread
  const int lrB = tid >> 2;         // 0..127
  const int lkB = (tid & 3) << 3;   // 0,8,16,24
  const float* ap = A + (size_t)(row0 + lrA) * KDIM + lkA;
  const float* bp = Bm + (size_t)(col0 + lrB) * KDIM + lkB;
  const int wr = (w >> 2) << 5;     // 0 or 32
  const int wc = (w & 3) << 5;      // 0,32,64,96
  const int li = lane & 15;
  const int lk4 = lane >> 4;

  // ---- C/D layout probe: decode (row,col) of each acc slot at runtime ----
  int rowof[4], colof[4];
  {
    f64x4v pr = {0.0, 0.0, 0.0, 0.0};
    f64x4v pc = {0.0, 0.0, 0.0, 0.0};
    const double vidx = (double)li;
    pr = __builtin_amdgcn_mfma_f64_16x16x4f64(vidx, 1.0, pr, 0, 0, 0);
    pc = __builtin_amdgcn_mfma_f64_16x16x4f64(1.0, vidx, pc, 0, 0, 0);
#pragma unroll
    for (int vj = 0; vj < 4; ++vj) {
      rowof[vj] = (int)(pr[vj] * 0.25 + 0.5);
      colof[vj] = (int)(pc[vj] * 0.25 + 0.5);
    }
  }

  f64x4v acc[2][2];
#pragma unroll
  for (int m = 0; m < 2; ++m)
#pragma unroll
    for (int n = 0; n < 2; ++n)
      acc[m][n] = (f64x4v){0.0, 0.0, 0.0, 0.0};

  // register prefetch one chunk ahead (3 float4 = 12 VGPR, spill-safe)
  float4 ra = *(const float4*)(ap);
  float4 rb0 = *(const float4*)(bp);
  float4 rb1 = *(const float4*)(bp + 4);
  for (int k0 = 0; k0 < KDIM; k0 += 32) {
    __syncthreads();   // previous chunk's readers done
    *(float4*)&As[lrA][lkA] = ra;
    *(float4*)&Bs[lrB][lkB] = rb0;
    *(float4*)&Bs[lrB][lkB + 4] = rb1;
    if (k0 + 32 < KDIM) {
      ra = *(const float4*)(ap + k0 + 32);
      rb0 = *(const float4*)(bp + k0 + 32);
      rb1 = *(const float4*)(bp + k0 + 36);
    }
    __syncthreads();
#pragma unroll
    for (int ks = 0; ks < 32; ks += 4) {
      const int kk = ks + lk4;
      const double af0 = (double)As[wr + li][kk];
      const double af1 = (double)As[wr + 16 + li][kk];
      const double bf0 = (double)Bs[wc + li][kk];
      const double bf1 = (double)Bs[wc + 16 + li][kk];
      acc[0][0] = __builtin_amdgcn_mfma_f64_16x16x4f64(af0, bf0, acc[0][0], 0, 0, 0);
      acc[0][1] = __builtin_amdgcn_mfma_f64_16x16x4f64(af0, bf1, acc[0][1], 0, 0, 0);
      acc[1][0] = __builtin_amdgcn_mfma_f64_16x16x4f64(af1, bf0, acc[1][0], 0, 0, 0);
      acc[1][1] = __builtin_amdgcn_mfma_f64_16x16x4f64(af1, bf1, acc[1][1], 0, 0, 0);
    }
  }

  const int bb = row0 >> 11;
  const int t0 = row0 & 2047;
#pragma unroll
  for (int m = 0; m < 2; ++m)
#pragma unroll
    for (int n = 0; n < 2; ++n)
#pragma unroll
      for (int vj = 0; vj < 4; ++vj) {
        const int r = wr + 16 * m + rowof[vj];         // row in tile (0..63)
        const int gc = col0 + wc + 16 * n + colof[vj]; // global qkv col
        const int qi = gc >> 10;                       // 0=q 1=k
        const int head = (gc & 1023) >> 6;
        const int d = gc & 63;
        const int t = t0 + r;
        const float fv = (float)acc[m][n][vj];
        float* dst = ((qi == 0) ? qbuf : kbuf) +
                     (size_t)(bb * NH + head) * SEQ_T * DH;
        dst[(size_t)t * DH + d] = fv;
        if (qi == 1) {
          unsigned short* kb = kbf + ((size_t)(bb * NH + head) << 17);
          const int key = t & 127;
          const int off =
              (((t >> 7) << 13) | (key << 6) | d) ^ ((key & 7) << 3);
          __hip_bfloat16 hb = __float2bfloat16(fv);
          kb[off] = *(unsigned short*)&hb;
        }
      }
}

// V projection (cols 2048..3071): split-bf16 MFMA, now 512-thread 64x128
// tile (the transform that took gemm_qk 317->293). Per-element accumulation
// chain (same k order, same Ah*Bh+Ah*Bl+Al*Bh triplet) unchanged — V is
// bit-identical to the round-4..8 passing versions.
// Bm passed pre-offset to wqkv + 2048*KDIM.
__global__ __launch_bounds__(512) void gemm_v(
    const float* __restrict__ A, const float* __restrict__ Bm,
    unsigned short* __restrict__ vbuf) {
  __shared__ __align__(16) unsigned short Ah[64][40];    // rows 80B
  __shared__ __align__(16) unsigned short Al[64][40];
  __shared__ __align__(16) unsigned short Bh[128][40];
  __shared__ __align__(16) unsigned short Bl[128][40];
  const int tid = threadIdx.x;
  const int lane = tid & 63;
  const int w = tid >> 6;            // 0..7
  const int row0 = blockIdx.y * 64;
  const int col0v = blockIdx.x * 128;     // V col (0..1023)
  const int lrA = tid >> 3;          // 0..63
  const int lkA = (tid & 7) << 2;    // 0..28 step 4
  const int lrB = tid >> 2;          // 0..127
  const int lkB = (tid & 3) << 3;    // 0,8,16,24
  const float* ap = A + (size_t)(row0 + lrA) * KDIM + lkA;
  const float* bp = Bm + (size_t)(col0v + lrB) * KDIM + lkB;
  const int wr = (w >> 2) << 5;      // 0 or 32
  const int wc = (w & 3) << 5;       // 0,32,64,96
  const int li = lane & 15;
  const int kA = (lane >> 4) << 3;   // frag k-run (verified bf16 map)

  f32x4v acc[2][2];
#pragma unroll
  for (int m = 0; m < 2; ++m)
#pragma unroll
    for (int n = 0; n < 2; ++n)
      acc[m][n] = (f32x4v){0.f, 0.f, 0.f, 0.f};

  float4 ra = *(const float4*)(ap);
  float4 rb0 = *(const float4*)(bp);
  float4 rb1 = *(const float4*)(bp + 4);
  for (int k0 = 0; k0 < KDIM; k0 += 32) {
    __syncthreads();
    split4(ra, &Ah[lrA][lkA], &Al[lrA][lkA]);
    split8(rb0, rb1, &Bh[lrB][lkB], &Bl[lrB][lkB]);
    if (k0 + 32 < KDIM) {
      ra = *(const float4*)(ap + k0 + 32);
      rb0 = *(const float4*)(bp + k0 + 32);
      rb1 = *(const float4*)(bp + k0 + 36);
    }
    __syncthreads();
    bf16x8v ah[2], al[2], bh[2], bl[2];
#pragma unroll
    for (int m = 0; m < 2; ++m) {
      ah[m] = *(const bf16x8v*)&Ah[wr + 16 * m + li][kA];
      al[m] = *(const bf16x8v*)&Al[wr + 16 * m + li][kA];
      bh[m] = *(const bf16x8v*)&Bh[wc + 16 * m + li][kA];
      bl[m] = *(const bf16x8v*)&Bl[wc + 16 * m + li][kA];
    }
#pragma unroll
    for (int m = 0; m < 2; ++m)
#pragma unroll
      for (int n = 0; n < 2; ++n) {
        acc[m][n] = __builtin_amdgcn_mfma_f32_16x16x32_bf16(ah[m], bh[n], acc[m][n], 0, 0, 0);
        acc[m][n] = __builtin_amdgcn_mfma_f32_16x16x32_bf16(ah[m], bl[n], acc[m][n], 0, 0, 0);
        acc[m][n] = __builtin_amdgcn_mfma_f32_16x16x32_bf16(al[m], bh[n], acc[m][n], 0, 0, 0);
      }
  }

  const int bb = row0 >> 11;
  const int t0 = row0 & 2047;
  const int r4 = (lane >> 4) << 2;   // C row base (verified bf16 C layout)
#pragma unroll
  for (int m = 0; m < 2; ++m)
#pragma unroll
    for (int n = 0; n < 2; ++n)
#pragma unroll
      for (int j = 0; j < 4; ++j) {
        const int t = t0 + wr + 16 * m + r4 + j;
        const int vcol = col0v + wc + 16 * n + li;
        const int head = vcol >> 6;
        const int d = vcol & 63;
        vbuf[(size_t)(bb * NH + head) * SEQ_T * DH + (size_t)t * DH + d] =
            (unsigned short)f2bs(acc[m][n][j]);
      }
}

// Attention, MFMA candidate-filter scheme — round-5/8 passing logic.
// This round: per-CU load balancing. Grid = 1024 blocks = exactly 4/CU
// (LDS 37.9KB), all co-resident; under round-robin dispatch CU c hosts
// groups {g0, g0+8, g0+16, g0+24} whose work nt(g)=g/2+1 summed ranges
// 28..42. Octant remap m(u) = {u, 23-u, u, 55-u} makes every quadruple
// sum to 62 -> balanced. Pure scheduling permutation, zero numeric change.
__global__ __launch_bounds__(256) void attn_topk(
    const float* __restrict__ q, const float* __restrict__ kmat,
    const unsigned short* __restrict__ kbf,
    const unsigned short* __restrict__ v, unsigned short* __restrict__ ctx) {
  __shared__ __align__(16) unsigned short kt[128 * 64];  // 16KB swizzled tile
  __shared__ double cs64[64][CAP];                       // 16KB exact scores
  __shared__ short ckey[64][CAP];                        // 4KB candidate keys
  __shared__ int ccnt[64];
  __shared__ double rthr[64];
  __shared__ float rmx[64];

  const int tid = threadIdx.x;
  const int lane = tid & 63;
  const int w = tid >> 6;
  const int bh = blockIdx.x & 31;
  const int u = blockIdx.x >> 5;
  int g;
  if (u < 8) g = u;
  else if (u < 16) g = 23 - u;
  else if (u < 24) g = u;
  else g = 55 - u;
  const int t0 = g << 6;
  const size_t kbase = (size_t)bh * SEQ_T * DH;
  const int wrow0 = t0 + (w << 4);
  const int kA = (lane >> 4) << 3;                 // A/B-frag k-run offset
  const int rbase = wrow0 + ((lane >> 4) << 2);    // C row of acc[0]

  // Q fragment (A operand): row = lane&15, k = 8*(lane>>4)+j (+32 for half 1)
  bf16x8v qa0, qa1;
  {
    const float* qr = q + kbase + (size_t)(wrow0 + (lane & 15)) * DH;
    const float4 x0 = *(const float4*)(qr + kA);
    const float4 x1 = *(const float4*)(qr + kA + 4);
    const float4 y0 = *(const float4*)(qr + 32 + kA);
    const float4 y1 = *(const float4*)(qr + 32 + kA + 4);
    qa0[0] = f2bs(x0.x); qa0[1] = f2bs(x0.y);
    qa0[2] = f2bs(x0.z); qa0[3] = f2bs(x0.w);
    qa0[4] = f2bs(x1.x); qa0[5] = f2bs(x1.y);
    qa0[6] = f2bs(x1.z); qa0[7] = f2bs(x1.w);
    qa1[0] = f2bs(y0.x); qa1[1] = f2bs(y0.y);
    qa1[2] = f2bs(y0.z); qa1[3] = f2bs(y0.w);
    qa1[4] = f2bs(y1.x); qa1[5] = f2bs(y1.y);
    qa1[6] = f2bs(y1.z); qa1[7] = f2bs(y1.w);
  }

  const uint4* ksrc = (const uint4*)(kbf + ((size_t)bh << 17));
  const int nt = (t0 >> 7) + 1;       // tiles covering keys 0..t0+63
  const int wmax = wrow0 + 15;

  float tq[4][8];
#pragma unroll
  for (int j = 0; j < 4; ++j)
#pragma unroll
    for (int m = 0; m < 8; ++m) tq[j][m] = -FLT_MAX;

  // ---- pass 1: MFMA scores + per-lane top-8 per slot ----
  for (int T = 0; T < nt; ++T) {
    if (T) __syncthreads();
    {
      const uint4* st = ksrc + (size_t)T * 1024;
      uint4* dv = (uint4*)kt;
#pragma unroll
      for (int i = 0; i < 4; ++i) dv[i * 256 + tid] = st[i * 256 + tid];
    }
    __syncthreads();
    const int glim0 = (wmax - (T << 7)) >> 4;
    const int glim = glim0 > 7 ? 7 : glim0;
    for (int gt = 0; gt <= glim; ++gt) {
      const int kk = (gt << 4) + (lane & 15);
      const int key = (T << 7) + kk;
      const int b0 = ((kk << 7) | (kA << 1)) ^ ((kk & 7) << 4);
      const int b1 = ((kk << 7) | ((32 + kA) << 1)) ^ ((kk & 7) << 4);
      const bf16x8v kb0 = *(const bf16x8v*)((const char*)kt + b0);
      const bf16x8v kb1 = *(const bf16x8v*)((const char*)kt + b1);
      f32x4v acc = {0.f, 0.f, 0.f, 0.f};
      acc = __builtin_amdgcn_mfma_f32_16x16x32_bf16(qa0, kb0, acc, 0, 0, 0);
      acc = __builtin_amdgcn_mfma_f32_16x16x32_bf16(qa1, kb1, acc, 0, 0, 0);
#pragma unroll
      for (int j = 0; j < 4; ++j) {
        float sc = acc[j] * 0.125f;
        sc = (key <= rbase + j) ? sc : -FLT_MAX;
        if (sc > tq[j][7]) {
          float s = sc;
#pragma unroll
          for (int m = 0; m < 8; ++m) {
            const float hi = fmaxf(tq[j][m], s);
            s = fminf(tq[j][m], s);
            tq[j][m] = hi;
          }
        }
      }
    }
  }

  // ---- merge per slot across the 16-lane group (4 bitonic rounds) ----
#pragma unroll
  for (int j = 0; j < 4; ++j) {
#pragma unroll
    for (int xm = 1; xm < 16; xm <<= 1) {
      float m[8];
#pragma unroll
      for (int i = 0; i < 8; ++i) {
        const float pb = __shfl_xor(tq[j][7 - i], xm);
        m[i] = fmaxf(tq[j][i], pb);
      }
#pragma unroll
      for (int d = 4; d >= 1; d >>= 1)
#pragma unroll
        for (int i = 0; i < 8; ++i)
          if ((i & d) == 0 && (i | d) < 8) {
            const float hi = fmaxf(m[i], m[i | d]);
            const float lo = fminf(m[i], m[i | d]);
            m[i] = hi;
            m[i | d] = lo;
          }
#pragma unroll
      for (int i = 0; i < 8; ++i) tq[j][i] = m[i];
    }
  }
  float thrj[4];
#pragma unroll
  for (int j = 0; j < 4; ++j) {
    const int kf = (rbase + j + 1 < KSEL) ? (rbase + j + 1) : KSEL;
    float th = tq[j][7];
#pragma unroll
    for (int m = 0; m < 8; ++m)
      if (m == kf - 1) th = tq[j][m];
    thrj[j] = th - MFMA_MARGIN;
  }

  if (tid < 64) ccnt[tid] = 0;
  __syncthreads();

  // ---- pass 2: identical MFMA re-scan, collect candidates ----
  for (int T = 0; T < nt; ++T) {
    if (T) __syncthreads();
    {
      const uint4* st = ksrc + (size_t)T * 1024;
      uint4* dv = (uint4*)kt;
#pragma unroll
      for (int i = 0; i < 4; ++i) dv[i * 256 + tid] = st[i * 256 + tid];
    }
    __syncthreads();
    const int glim0 = (wmax - (T << 7)) >> 4;
    const int glim = glim0 > 7 ? 7 : glim0;
    for (int gt = 0; gt <= glim; ++gt) {
      const int kk = (gt << 4) + (lane & 15);
      const int key = (T << 7) + kk;
      const int b0 = ((kk << 7) | (kA << 1)) ^ ((kk & 7) << 4);
      const int b1 = ((kk << 7) | ((32 + kA) << 1)) ^ ((kk & 7) << 4);
      const bf16x8v kb0 = *(const bf16x8v*)((const char*)kt + b0);
      const bf16x8v kb1 = *(const bf16x8v*)((const char*)kt + b1);
      f32x4v acc = {0.f, 0.f, 0.f, 0.f};
      acc = __builtin_amdgcn_mfma_f32_16x16x32_bf16(qa0, kb0, acc, 0, 0, 0);
      acc = __builtin_amdgcn_mfma_f32_16x16x32_bf16(qa1, kb1, acc, 0, 0, 0);
#pragma unroll
      for (int j = 0; j < 4; ++j) {
        const float sc = acc[j] * 0.125f;
        if (key <= rbase + j && sc >= thrj[j]) {
          const int rl = (w << 4) + ((lane >> 4) << 2) + j;
          const int p = atomicAdd(&ccnt[rl], 1);
          if (p < CAP) ckey[rl][p] = (short)key;
        }
      }
    }
  }

  // ---- phase 3A: exact fp64 rescore, lane-per-candidate, 2 rows/iter ----
  const int lid = lane & 31;
  for (int rp = 0; rp < 8; ++rp) {
    const int rl = (w << 4) + (rp << 1) + (lane >> 5);
    const int ncc = ccnt[rl] < CAP ? ccnt[rl] : CAP;
    if (lid < ncc) {
      const int key = ckey[rl][lid];
      const float* qr = q + kbase + (size_t)(t0 + rl) * DH;
      const float* kr = kmat + kbase + (size_t)key * DH;
      double s = 0.0;
#pragma unroll
      for (int d4 = 0; d4 < 16; ++d4) {
        const float4 qq = *(const float4*)(qr + (d4 << 2));
        const float4 kq = *(const float4*)(kr + (d4 << 2));
        s = fma((double)qq.x, (double)kq.x, s);
        s = fma((double)qq.y, (double)kq.y, s);
        s = fma((double)qq.z, (double)kq.z, s);
        s = fma((double)qq.w, (double)kq.w, s);
      }
      cs64[rl][lid] = s * 0.125;
    }
  }
  __syncthreads();

  // ---- phase 3B: per-row fp64 top-8 + threshold (row per lane) ----
  if (lane < 16) {
    const int rl = (w << 4) + lane;
    const int trow = t0 + rl;
    const int ncc = ccnt[rl] < CAP ? ccnt[rl] : CAP;
    double a64[8];
#pragma unroll
    for (int j = 0; j < 8; ++j) a64[j] = -DBL_MAX;
    for (int l = 0; l < ncc; ++l) {
      double sv = cs64[rl][l];
#pragma unroll
      for (int j = 0; j < 8; ++j) {
        const double hi = fmax(a64[j], sv);
        sv = fmin(a64[j], sv);
        a64[j] = hi;
      }
    }
    const int kf = (trow + 1 < KSEL) ? (trow + 1) : KSEL;
    double th = a64[7];
#pragma unroll
    for (int j = 0; j < 8; ++j)
      if (j == kf - 1) th = a64[j];
    rthr[rl] = th;
    rmx[rl] = (float)a64[0];
  }
  __syncthreads();

  // ---- phase 3C: sparse softmax * V, 4 interleaved row-chains ----
  for (int rg = 0; rg < 4; ++rg) {
    const int rlb = (w << 4) + (rg << 2);
    float acv[4] = {0.f, 0.f, 0.f, 0.f};
    float Zs[4] = {0.f, 0.f, 0.f, 0.f};
    int ncs[4];
    double ths[4];
    float mxs[4];
#pragma unroll
    for (int j = 0; j < 4; ++j) {
      const int rl = rlb + j;
      ncs[j] = ccnt[rl] < CAP ? ccnt[rl] : CAP;
      ths[j] = rthr[rl];
      mxs[j] = rmx[rl];
    }
    int nmax = ncs[0];
#pragma unroll
    for (int j = 1; j < 4; ++j) nmax = ncs[j] > nmax ? ncs[j] : nmax;
    for (int l = 0; l < nmax; ++l) {
#pragma unroll
      for (int j = 0; j < 4; ++j) {
        const int rl = rlb + j;
        if (l < ncs[j]) {
          const double s = cs64[rl][l];
          const float wgl = (s >= ths[j]) ? expf((float)s - mxs[j]) : 0.f;
          Zs[j] += wgl;
          acv[j] = fmaf(
              wgl,
              bf2f((unsigned int)v[kbase + (size_t)ckey[rl][l] * DH + lane]),
              acv[j]);
        }
      }
    }
#pragma unroll
    for (int j = 0; j < 4; ++j) {
      const int trow = t0 + rlb + j;
      __hip_bfloat16 h = __float2bfloat16(acv[j] / Zs[j]);
      ctx[((size_t)(bh >> 4) * SEQ_T + trow) * DIM_D + (bh & 15) * DH + lane] =
          *(unsigned short*)&h;
    }
  }
}

// Output projection via MFMA: A = ctx (exactly bf16), B = wout split to
// hi+lo bf16; C = A*Bh + A*Bl in fp32 accumulators (~1.6e-5 rel error vs
// fp32 chain — output threshold is 0.0765).
__global__ __launch_bounds__(256) void gemm_out(
    const unsigned short* __restrict__ A, const float* __restrict__ Bm,
    float* __restrict__ obuf) {
  __shared__ __align__(16) unsigned short Ah[64][40];
  __shared__ __align__(16) unsigned short Bh[64][40];
  __shared__ __align__(16) unsigned short Bl[64][40];
  const int tid = threadIdx.x;
  const int lane = tid & 63;
  const int w = tid >> 6;
  const int row0 = blockIdx.y * 64;
  const int col0 = blockIdx.x * 64;
  const int lrow = tid >> 2;
  const int lk = (tid & 3) << 3;
  const unsigned short* ap = A + (size_t)(row0 + lrow) * KDIM + lk;
  const float* bp = Bm + (size_t)(col0 + lrow) * KDIM + lk;
  const int wr = (w >> 1) << 5;
  const int wc = (w & 1) << 5;
  const int li = lane & 15;
  const int kA = (lane >> 4) << 3;

  f32x4v acc[2][2];
#pragma unroll
  for (int m = 0; m < 2; ++m)
#pragma unroll
    for (int n = 0; n < 2; ++n)
      acc[m][n] = (f32x4v){0.f, 0.f, 0.f, 0.f};

  uint4 ua = *(const uint4*)(ap);
  float4 rb0 = *(const float4*)(bp);
  float4 rb1 = *(const float4*)(bp + 4);
  for (int k0 = 0; k0 < KDIM; k0 += 32) {
    __syncthreads();
    *(uint4*)&Ah[lrow][lk] = ua;
    split8(rb0, rb1, &Bh[lrow][lk], &Bl[lrow][lk]);
    if (k0 + 32 < KDIM) {
      ua = *(const uint4*)(ap + k0 + 32);
      rb0 = *(const float4*)(bp + k0 + 32);
      rb1 = *(const float4*)(bp + k0 + 36);
    }
    __syncthreads();
    bf16x8v ah[2], bh[2], bl[2];
#pragma unroll
    for (int m = 0; m < 2; ++m) {
      ah[m] = *(const bf16x8v*)&Ah[wr + 16 * m + li][kA];
      bh[m] = *(const bf16x8v*)&Bh[wc + 16 * m + li][kA];
      bl[m] = *(const bf16x8v*)&Bl[wc + 16 * m + li][kA];
    }
#pragma unroll
    for (int m = 0; m < 2; ++m)
#pragma unroll
      for (int n = 0; n < 2; ++n) {
        acc[m][n] = __builtin_amdgcn_mfma_f32_16x16x32_bf16(ah[m], bh[n], acc[m][n], 0, 0, 0);
        acc[m][n] = __builtin_amdgcn_mfma_f32_16x16x32_bf16(ah[m], bl[n], acc[m][n], 0, 0, 0);
      }
  }

  const int r4 = (lane >> 4) << 2;
#pragma unroll
  for (int m = 0; m < 2; ++m)
#pragma unroll
    for (int n = 0; n < 2; ++n)
#pragma unroll
      for (int j = 0; j < 4; ++j) {
        const int r = row0 + wr + 16 * m + r4 + j;
        const int c = col0 + wc + 16 * n + li;
        obuf[(size_t)r * DIM_D + c] = acc[m][n][j];
      }
}

extern "C" void kernel_launch(void* const* d_in, const int* in_sizes, int n_in,
                              void* d_out, int out_size, void* d_ws,
                              size_t ws_size, hipStream_t stream) {
  (void)out_size; (void)ws_size;
  const float* x = (const float*)d_in[0];
  const float* wqkv = (const float*)d_in[1];
  const float* wout = (const float*)d_in[2];
  for (int i = 0; i < n_in; ++i) {
    if (in_sizes[i] == NUM_B * SEQ_T * DIM_D) x = (const float*)d_in[i];
    else if (in_sizes[i] == 3 * DIM_D * DIM_D) wqkv = (const float*)d_in[i];
    else if (in_sizes[i] == DIM_D * DIM_D) wout = (const float*)d_in[i];
  }
  float* out = (float*)d_out;

  const size_t qkv_elems = (size_t)NUM_B * NH * SEQ_T * DH;   // 4.19M
  float* qbuf = (float*)d_ws;
  float* kbuf = qbuf + qkv_elems;
  unsigned short* vbuf = (unsigned short*)(kbuf + qkv_elems);
  unsigned short* ctxb = vbuf + qkv_elems;
  unsigned short* kbf = ctxb + (size_t)NUM_B * SEQ_T * DIM_D;  // bf16 K tiles

  gemm_qk<<<dim3(2 * DIM_D / 128, NUM_B * SEQ_T / 64), 512, 0, stream>>>(
      x, wqkv, qbuf, kbuf, kbf);
  gemm_v<<<dim3(DIM_D / 128, NUM_B * SEQ_T / 64), 512, 0, stream>>>(
      x, wqkv + (size_t)2 * DIM_D * KDIM, vbuf);
  attn_topk<<<dim3(NUM_B * NH * (SEQ_T / 64)), 256, 0, stream>>>(
      qbuf, kbuf, kbf, vbuf, ctxb);
  gemm_out<<<dim3(DIM_D / 64, NUM_B * SEQ_T / 64), 256, 0, stream>>>(
      ctxb, wout, out);
}

// Round 10
// 591.796 us; speedup vs baseline: 1.2737x; 1.0010x over previous
//
#include <hip/hip_runtime.h>
#include <hip/hip_bf16.h>
#include <math.h>
#include <float.h>

#define NUM_B 2
#define SEQ_T 2048
#define DIM_D 1024
#define NH 16
#define DH 64
#define KDIM 1024
#define KSEL 8

// attention candidate scheme
#define CAP 32
#define MFMA_MARGIN 0.06f

typedef __attribute__((ext_vector_type(8))) short bf16x8v;   // 8 bf16 (4 VGPR)
typedef __attribute__((ext_vector_type(4))) float f32x4v;    // MFMA acc
typedef __attribute__((ext_vector_type(4))) double f64x4v;   // f64 MFMA acc

__device__ __forceinline__ float bf2f(unsigned int u) {
  union { unsigned int i; float f; } v; v.i = u << 16; return v.f;
}

__device__ __forceinline__ short f2bs(float f) {
  __hip_bfloat16 h = __float2bfloat16(f);
  return *(short*)&h;
}

// split x into hi+lo bf16 (residual ~1.6e-5 rel); store 8 to LDS as 16B each
__device__ __forceinline__ void split8(float4 x0, float4 x1,
                                       unsigned short* __restrict__ hp,
                                       unsigned short* __restrict__ lp) {
  unsigned short h[8], l[8];
  const float xs[8] = {x0.x, x0.y, x0.z, x0.w, x1.x, x1.y, x1.z, x1.w};
#pragma unroll
  for (int j = 0; j < 8; ++j) {
    const short hb = f2bs(xs[j]);
    h[j] = (unsigned short)hb;
    const float hf = bf2f((unsigned int)(unsigned short)hb);
    l[j] = (unsigned short)f2bs(xs[j] - hf);
  }
  *(uint4*)hp = *(const uint4*)h;
  *(uint4*)lp = *(const uint4*)l;
}

// split 4 floats into hi+lo bf16; store as 8B each
__device__ __forceinline__ void split4(float4 x,
                                       unsigned short* __restrict__ hp,
                                       unsigned short* __restrict__ lp) {
  unsigned short h[4], l[4];
  const float xs[4] = {x.x, x.y, x.z, x.w};
#pragma unroll
  for (int j = 0; j < 4; ++j) {
    const short hb = f2bs(xs[j]);
    h[j] = (unsigned short)hb;
    const float hf = bf2f((unsigned int)(unsigned short)hb);
    l[j] = (unsigned short)f2bs(xs[j] - hf);
  }
  *(uint2*)hp = *(const uint2*)h;
  *(uint2*)lp = *(const uint2*)l;
}

// Q,K projection (cols 0..2047 of qkv): fp64 accumulation via
// v_mfma_f64_16x16x4. Per-wave k-order ascending 0..1023 in 4-k steps —
// BIT-IDENTICAL Q/K (selection-critical). Round-8/9 passing version:
// 512 threads, 64x128 tile, MfmaUtil 80% (295us; ceiling ~236 at 100%).
// C/D layout decoded at runtime with probe MFMAs (round-2 lesson).
// Also emits kbf: bf16 K image, XOR-swizzled for attn's linear staging.
__global__ __launch_bounds__(512) void gemm_qk(
    const float* __restrict__ A, const float* __restrict__ Bm,
    float* __restrict__ qbuf, float* __restrict__ kbuf,
    unsigned short* __restrict__ kbf) {
  __shared__ __align__(16) float As[64][36];    // row-major, +4 pad
  __shared__ __align__(16) float Bs[128][36];
  const int tid = threadIdx.x;
  const int lane = tid & 63;
  const int w = tid >> 6;           // 0..7
  const int row0 = blockIdx.y * 64;
  const int col0 = blockIdx.x * 128;
  const int lrA = tid >> 3;         // 0..63
  const int lkA = (tid & 7) << 2;   // 0..28 step 4
  const int lrB = tid >> 2;         // 0..127
  const int lkB = (tid & 3) << 3;   // 0,8,16,24
  const float* ap = A + (size_t)(row0 + lrA) * KDIM + lkA;
  const float* bp = Bm + (size_t)(col0 + lrB) * KDIM + lkB;
  const int wr = (w >> 2) << 5;     // 0 or 32
  const int wc = (w & 3) << 5;      // 0,32,64,96
  const int li = lane & 15;
  const int lk4 = lane >> 4;

  // ---- C/D layout probe: decode (row,col) of each acc slot at runtime ----
  int rowof[4], colof[4];
  {
    f64x4v pr = {0.0, 0.0, 0.0, 0.0};
    f64x4v pc = {0.0, 0.0, 0.0, 0.0};
    const double vidx = (double)li;
    pr = __builtin_amdgcn_mfma_f64_16x16x4f64(vidx, 1.0, pr, 0, 0, 0);
    pc = __builtin_amdgcn_mfma_f64_16x16x4f64(1.0, vidx, pc, 0, 0, 0);
#pragma unroll
    for (int vj = 0; vj < 4; ++vj) {
      rowof[vj] = (int)(pr[vj] * 0.25 + 0.5);
      colof[vj] = (int)(pc[vj] * 0.25 + 0.5);
    }
  }

  f64x4v acc[2][2];
#pragma unroll
  for (int m = 0; m < 2; ++m)
#pragma unroll
    for (int n = 0; n < 2; ++n)
      acc[m][n] = (f64x4v){0.0, 0.0, 0.0, 0.0};

  // register prefetch one chunk ahead (3 float4 = 12 VGPR, spill-safe)
  float4 ra = *(const float4*)(ap);
  float4 rb0 = *(const float4*)(bp);
  float4 rb1 = *(const float4*)(bp + 4);
  for (int k0 = 0; k0 < KDIM; k0 += 32) {
    __syncthreads();   // previous chunk's readers done
    *(float4*)&As[lrA][lkA] = ra;
    *(float4*)&Bs[lrB][lkB] = rb0;
    *(float4*)&Bs[lrB][lkB + 4] = rb1;
    if (k0 + 32 < KDIM) {
      ra = *(const float4*)(ap + k0 + 32);
      rb0 = *(const float4*)(bp + k0 + 32);
      rb1 = *(const float4*)(bp + k0 + 36);
    }
    __syncthreads();
#pragma unroll
    for (int ks = 0; ks < 32; ks += 4) {
      const int kk = ks + lk4;
      const double af0 = (double)As[wr + li][kk];
      const double af1 = (double)As[wr + 16 + li][kk];
      const double bf0 = (double)Bs[wc + li][kk];
      const double bf1 = (double)Bs[wc + 16 + li][kk];
      acc[0][0] = __builtin_amdgcn_mfma_f64_16x16x4f64(af0, bf0, acc[0][0], 0, 0, 0);
      acc[0][1] = __builtin_amdgcn_mfma_f64_16x16x4f64(af0, bf1, acc[0][1], 0, 0, 0);
      acc[1][0] = __builtin_amdgcn_mfma_f64_16x16x4f64(af1, bf0, acc[1][0], 0, 0, 0);
      acc[1][1] = __builtin_amdgcn_mfma_f64_16x16x4f64(af1, bf1, acc[1][1], 0, 0, 0);
    }
  }

  const int bb = row0 >> 11;
  const int t0 = row0 & 2047;
#pragma unroll
  for (int m = 0; m < 2; ++m)
#pragma unroll
    for (int n = 0; n < 2; ++n)
#pragma unroll
      for (int vj = 0; vj < 4; ++vj) {
        const int r = wr + 16 * m + rowof[vj];         // row in tile (0..63)
        const int gc = col0 + wc + 16 * n + colof[vj]; // global qkv col
        const int qi = gc >> 10;                       // 0=q 1=k
        const int head = (gc & 1023) >> 6;
        const int d = gc & 63;
        const int t = t0 + r;
        const float fv = (float)acc[m][n][vj];
        float* dst = ((qi == 0) ? qbuf : kbuf) +
                     (size_t)(bb * NH + head) * SEQ_T * DH;
        dst[(size_t)t * DH + d] = fv;
        if (qi == 1) {
          unsigned short* kb = kbf + ((size_t)(bb * NH + head) << 17);
          const int key = t & 127;
          const int off =
              (((t >> 7) << 13) | (key << 6) | d) ^ ((key & 7) << 3);
          __hip_bfloat16 hb = __float2bfloat16(fv);
          kb[off] = *(unsigned short*)&hb;
        }
      }
}

// V projection (cols 2048..3071): split-bf16 MFMA, 512-thread 64x128 tile
// (round-9 passing version). Per-element accumulation chain unchanged —
// V bit-identical. Bm passed pre-offset to wqkv + 2048*KDIM.
__global__ __launch_bounds__(512) void gemm_v(
    const float* __restrict__ A, const float* __restrict__ Bm,
    unsigned short* __restrict__ vbuf) {
  __shared__ __align__(16) unsigned short Ah[64][40];    // rows 80B
  __shared__ __align__(16) unsigned short Al[64][40];
  __shared__ __align__(16) unsigned short Bh[128][40];
  __shared__ __align__(16) unsigned short Bl[128][40];
  const int tid = threadIdx.x;
  const int lane = tid & 63;
  const int w = tid >> 6;            // 0..7
  const int row0 = blockIdx.y * 64;
  const int col0v = blockIdx.x * 128;     // V col (0..1023)
  const int lrA = tid >> 3;          // 0..63
  const int lkA = (tid & 7) << 2;    // 0..28 step 4
  const int lrB = tid >> 2;          // 0..127
  const int lkB = (tid & 3) << 3;    // 0,8,16,24
  const float* ap = A + (size_t)(row0 + lrA) * KDIM + lkA;
  const float* bp = Bm + (size_t)(col0v + lrB) * KDIM + lkB;
  const int wr = (w >> 2) << 5;      // 0 or 32
  const int wc = (w & 3) << 5;       // 0,32,64,96
  const int li = lane & 15;
  const int kA = (lane >> 4) << 3;   // frag k-run (verified bf16 map)

  f32x4v acc[2][2];
#pragma unroll
  for (int m = 0; m < 2; ++m)
#pragma unroll
    for (int n = 0; n < 2; ++n)
      acc[m][n] = (f32x4v){0.f, 0.f, 0.f, 0.f};

  float4 ra = *(const float4*)(ap);
  float4 rb0 = *(const float4*)(bp);
  float4 rb1 = *(const float4*)(bp + 4);
  for (int k0 = 0; k0 < KDIM; k0 += 32) {
    __syncthreads();
    split4(ra, &Ah[lrA][lkA], &Al[lrA][lkA]);
    split8(rb0, rb1, &Bh[lrB][lkB], &Bl[lrB][lkB]);
    if (k0 + 32 < KDIM) {
      ra = *(const float4*)(ap + k0 + 32);
      rb0 = *(const float4*)(bp + k0 + 32);
      rb1 = *(const float4*)(bp + k0 + 36);
    }
    __syncthreads();
    bf16x8v ah[2], al[2], bh[2], bl[2];
#pragma unroll
    for (int m = 0; m < 2; ++m) {
      ah[m] = *(const bf16x8v*)&Ah[wr + 16 * m + li][kA];
      al[m] = *(const bf16x8v*)&Al[wr + 16 * m + li][kA];
      bh[m] = *(const bf16x8v*)&Bh[wc + 16 * m + li][kA];
      bl[m] = *(const bf16x8v*)&Bl[wc + 16 * m + li][kA];
    }
#pragma unroll
    for (int m = 0; m < 2; ++m)
#pragma unroll
      for (int n = 0; n < 2; ++n) {
        acc[m][n] = __builtin_amdgcn_mfma_f32_16x16x32_bf16(ah[m], bh[n], acc[m][n], 0, 0, 0);
        acc[m][n] = __builtin_amdgcn_mfma_f32_16x16x32_bf16(ah[m], bl[n], acc[m][n], 0, 0, 0);
        acc[m][n] = __builtin_amdgcn_mfma_f32_16x16x32_bf16(al[m], bh[n], acc[m][n], 0, 0, 0);
      }
  }

  const int bb = row0 >> 11;
  const int t0 = row0 & 2047;
  const int r4 = (lane >> 4) << 2;   // C row base (verified bf16 C layout)
#pragma unroll
  for (int m = 0; m < 2; ++m)
#pragma unroll
    for (int n = 0; n < 2; ++n)
#pragma unroll
      for (int j = 0; j < 4; ++j) {
        const int t = t0 + wr + 16 * m + r4 + j;
        const int vcol = col0v + wc + 16 * n + li;
        const int head = vcol >> 6;
        const int d = vcol & 63;
        vbuf[(size_t)(bb * NH + head) * SEQ_T * DH + (size_t)t * DH + d] =
            (unsigned short)f2bs(acc[m][n][j]);
      }
}

// Attention, MFMA candidate-filter scheme. This round: 512 threads /
// 128 q-rows per block (8 waves x 16 rows) — each staged 16KB K-tile now
// feeds 8 waves instead of 4, halving total tile-sweeps (9216 -> 4352 per
// pass) and barrier drains per row. Per-wave per-row code is byte-identical
// to the round-9 passing version -> bit-exact output. 512 blocks = 2/CU
// (58KB LDS), 16 waves/CU (same as before). Balance: g = u<8 ? u : 23-u
// makes each CU's block pair sum to nt1+nt2 = 17 (constant).
__global__ __launch_bounds__(512) void attn_topk(
    const float* __restrict__ q, const float* __restrict__ kmat,
    const unsigned short* __restrict__ kbf,
    const unsigned short* __restrict__ v, unsigned short* __restrict__ ctx) {
  __shared__ __align__(16) unsigned short kt[128 * 64];  // 16KB swizzled tile
  __shared__ double cs64[128][CAP];                      // 32KB exact scores
  __shared__ short ckey[128][CAP];                       // 8KB candidate keys
  __shared__ int ccnt[128];
  __shared__ double rthr[128];
  __shared__ float rmx[128];

  const int tid = threadIdx.x;
  const int lane = tid & 63;
  const int w = tid >> 6;            // 0..7
  const int bh = blockIdx.x & 31;
  const int u = blockIdx.x >> 5;     // 0..15
  const int g = (u < 8) ? u : 23 - u;
  const int t0 = g << 7;             // 128-row group base
  const size_t kbase = (size_t)bh * SEQ_T * DH;
  const int wrow0 = t0 + (w << 4);
  const int kA = (lane >> 4) << 3;                 // A/B-frag k-run offset
  const int rbase = wrow0 + ((lane >> 4) << 2);    // C row of acc[0]

  // Q fragment (A operand): row = lane&15, k = 8*(lane>>4)+j (+32 for half 1)
  bf16x8v qa0, qa1;
  {
    const float* qr = q + kbase + (size_t)(wrow0 + (lane & 15)) * DH;
    const float4 x0 = *(const float4*)(qr + kA);
    const float4 x1 = *(const float4*)(qr + kA + 4);
    const float4 y0 = *(const float4*)(qr + 32 + kA);
    const float4 y1 = *(const float4*)(qr + 32 + kA + 4);
    qa0[0] = f2bs(x0.x); qa0[1] = f2bs(x0.y);
    qa0[2] = f2bs(x0.z); qa0[3] = f2bs(x0.w);
    qa0[4] = f2bs(x1.x); qa0[5] = f2bs(x1.y);
    qa0[6] = f2bs(x1.z); qa0[7] = f2bs(x1.w);
    qa1[0] = f2bs(y0.x); qa1[1] = f2bs(y0.y);
    qa1[2] = f2bs(y0.z); qa1[3] = f2bs(y0.w);
    qa1[4] = f2bs(y1.x); qa1[5] = f2bs(y1.y);
    qa1[6] = f2bs(y1.z); qa1[7] = f2bs(y1.w);
  }

  const uint4* ksrc = (const uint4*)(kbf + ((size_t)bh << 17));
  const int nt = (t0 >> 7) + 1;       // = g+1 tiles cover keys 0..t0+127
  const int wmax = wrow0 + 15;

  float tq[4][8];
#pragma unroll
  for (int j = 0; j < 4; ++j)
#pragma unroll
    for (int m = 0; m < 8; ++m) tq[j][m] = -FLT_MAX;

  // ---- pass 1: MFMA scores + per-lane top-8 per slot ----
  for (int T = 0; T < nt; ++T) {
    if (T) __syncthreads();
    {
      const uint4* st = ksrc + (size_t)T * 1024;
      uint4* dv = (uint4*)kt;
#pragma unroll
      for (int i = 0; i < 2; ++i) dv[i * 512 + tid] = st[i * 512 + tid];
    }
    __syncthreads();
    const int glim0 = (wmax - (T << 7)) >> 4;
    const int glim = glim0 > 7 ? 7 : glim0;
    for (int gt = 0; gt <= glim; ++gt) {
      const int kk = (gt << 4) + (lane & 15);
      const int key = (T << 7) + kk;
      const int b0 = ((kk << 7) | (kA << 1)) ^ ((kk & 7) << 4);
      const int b1 = ((kk << 7) | ((32 + kA) << 1)) ^ ((kk & 7) << 4);
      const bf16x8v kb0 = *(const bf16x8v*)((const char*)kt + b0);
      const bf16x8v kb1 = *(const bf16x8v*)((const char*)kt + b1);
      f32x4v acc = {0.f, 0.f, 0.f, 0.f};
      acc = __builtin_amdgcn_mfma_f32_16x16x32_bf16(qa0, kb0, acc, 0, 0, 0);
      acc = __builtin_amdgcn_mfma_f32_16x16x32_bf16(qa1, kb1, acc, 0, 0, 0);
#pragma unroll
      for (int j = 0; j < 4; ++j) {
        float sc = acc[j] * 0.125f;
        sc = (key <= rbase + j) ? sc : -FLT_MAX;
        if (sc > tq[j][7]) {
          float s = sc;
#pragma unroll
          for (int m = 0; m < 8; ++m) {
            const float hi = fmaxf(tq[j][m], s);
            s = fminf(tq[j][m], s);
            tq[j][m] = hi;
          }
        }
      }
    }
  }

  // ---- merge per slot across the 16-lane group (4 bitonic rounds) ----
#pragma unroll
  for (int j = 0; j < 4; ++j) {
#pragma unroll
    for (int xm = 1; xm < 16; xm <<= 1) {
      float m[8];
#pragma unroll
      for (int i = 0; i < 8; ++i) {
        const float pb = __shfl_xor(tq[j][7 - i], xm);
        m[i] = fmaxf(tq[j][i], pb);
      }
#pragma unroll
      for (int d = 4; d >= 1; d >>= 1)
#pragma unroll
        for (int i = 0; i < 8; ++i)
          if ((i & d) == 0 && (i | d) < 8) {
            const float hi = fmaxf(m[i], m[i | d]);
            const float lo = fminf(m[i], m[i | d]);
            m[i] = hi;
            m[i | d] = lo;
          }
#pragma unroll
      for (int i = 0; i < 8; ++i) tq[j][i] = m[i];
    }
  }
  float thrj[4];
#pragma unroll
  for (int j = 0; j < 4; ++j) {
    const int kf = (rbase + j + 1 < KSEL) ? (rbase + j + 1) : KSEL;
    float th = tq[j][7];
#pragma unroll
    for (int m = 0; m < 8; ++m)
      if (m == kf - 1) th = tq[j][m];
    thrj[j] = th - MFMA_MARGIN;
  }

  if (tid < 128) ccnt[tid] = 0;
  __syncthreads();

  // ---- pass 2: identical MFMA re-scan, collect candidates ----
  for (int T = 0; T < nt; ++T) {
    if (T) __syncthreads();
    {
      const uint4* st = ksrc + (size_t)T * 1024;
      uint4* dv = (uint4*)kt;
#pragma unroll
      for (int i = 0; i < 2; ++i) dv[i * 512 + tid] = st[i * 512 + tid];
    }
    __syncthreads();
    const int glim0 = (wmax - (T << 7)) >> 4;
    const int glim = glim0 > 7 ? 7 : glim0;
    for (int gt = 0; gt <= glim; ++gt) {
      const int kk = (gt << 4) + (lane & 15);
      const int key = (T << 7) + kk;
      const int b0 = ((kk << 7) | (kA << 1)) ^ ((kk & 7) << 4);
      const int b1 = ((kk << 7) | ((32 + kA) << 1)) ^ ((kk & 7) << 4);
      const bf16x8v kb0 = *(const bf16x8v*)((const char*)kt + b0);
      const bf16x8v kb1 = *(const bf16x8v*)((const char*)kt + b1);
      f32x4v acc = {0.f, 0.f, 0.f, 0.f};
      acc = __builtin_amdgcn_mfma_f32_16x16x32_bf16(qa0, kb0, acc, 0, 0, 0);
      acc = __builtin_amdgcn_mfma_f32_16x16x32_bf16(qa1, kb1, acc, 0, 0, 0);
#pragma unroll
      for (int j = 0; j < 4; ++j) {
        const float sc = acc[j] * 0.125f;
        if (key <= rbase + j && sc >= thrj[j]) {
          const int rl = (w << 4) + ((lane >> 4) << 2) + j;
          const int p = atomicAdd(&ccnt[rl], 1);
          if (p < CAP) ckey[rl][p] = (short)key;
        }
      }
    }
  }

  // ---- phase 3A: exact fp64 rescore, lane-per-candidate, 2 rows/iter ----
  const int lid = lane & 31;
  for (int rp = 0; rp < 8; ++rp) {
    const int rl = (w << 4) + (rp << 1) + (lane >> 5);
    const int ncc = ccnt[rl] < CAP ? ccnt[rl] : CAP;
    if (lid < ncc) {
      const int key = ckey[rl][lid];
      const float* qr = q + kbase + (size_t)(t0 + rl) * DH;
      const float* kr = kmat + kbase + (size_t)key * DH;
      double s = 0.0;
#pragma unroll
      for (int d4 = 0; d4 < 16; ++d4) {
        const float4 qq = *(const float4*)(qr + (d4 << 2));
        const float4 kq = *(const float4*)(kr + (d4 << 2));
        s = fma((double)qq.x, (double)kq.x, s);
        s = fma((double)qq.y, (double)kq.y, s);
        s = fma((double)qq.z, (double)kq.z, s);
        s = fma((double)qq.w, (double)kq.w, s);
      }
      cs64[rl][lid] = s * 0.125;
    }
  }
  __syncthreads();

  // ---- phase 3B: per-row fp64 top-8 + threshold (row per lane) ----
  if (lane < 16) {
    const int rl = (w << 4) + lane;
    const int trow = t0 + rl;
    const int ncc = ccnt[rl] < CAP ? ccnt[rl] : CAP;
    double a64[8];
#pragma unroll
    for (int j = 0; j < 8; ++j) a64[j] = -DBL_MAX;
    for (int l = 0; l < ncc; ++l) {
      double sv = cs64[rl][l];
#pragma unroll
      for (int j = 0; j < 8; ++j) {
        const double hi = fmax(a64[j], sv);
        sv = fmin(a64[j], sv);
        a64[j] = hi;
      }
    }
    const int kf = (trow + 1 < KSEL) ? (trow + 1) : KSEL;
    double th = a64[7];
#pragma unroll
    for (int j = 0; j < 8; ++j)
      if (j == kf - 1) th = a64[j];
    rthr[rl] = th;
    rmx[rl] = (float)a64[0];
  }
  __syncthreads();

  // ---- phase 3C: sparse softmax * V, 4 interleaved row-chains ----
  for (int rg = 0; rg < 4; ++rg) {
    const int rlb = (w << 4) + (rg << 2);
    float acv[4] = {0.f, 0.f, 0.f, 0.f};
    float Zs[4] = {0.f, 0.f, 0.f, 0.f};
    int ncs[4];
    double ths[4];
    float mxs[4];
#pragma unroll
    for (int j = 0; j < 4; ++j) {
      const int rl = rlb + j;
      ncs[j] = ccnt[rl] < CAP ? ccnt[rl] : CAP;
      ths[j] = rthr[rl];
      mxs[j] = rmx[rl];
    }
    int nmax = ncs[0];
#pragma unroll
    for (int j = 1; j < 4; ++j) nmax = ncs[j] > nmax ? ncs[j] : nmax;
    for (int l = 0; l < nmax; ++l) {
#pragma unroll
      for (int j = 0; j < 4; ++j) {
        const int rl = rlb + j;
        if (l < ncs[j]) {
          const double s = cs64[rl][l];
          const float wgl = (s >= ths[j]) ? expf((float)s - mxs[j]) : 0.f;
          Zs[j] += wgl;
          acv[j] = fmaf(
              wgl,
              bf2f((unsigned int)v[kbase + (size_t)ckey[rl][l] * DH + lane]),
              acv[j]);
        }
      }
    }
#pragma unroll
    for (int j = 0; j < 4; ++j) {
      const int trow = t0 + rlb + j;
      __hip_bfloat16 h = __float2bfloat16(acv[j] / Zs[j]);
      ctx[((size_t)(bh >> 4) * SEQ_T + trow) * DIM_D + (bh & 15) * DH + lane] =
          *(unsigned short*)&h;
    }
  }
}

// Output projection via MFMA: A = ctx (exactly bf16), B = wout split to
// hi+lo bf16; C = A*Bh + A*Bl in fp32 accumulators (~1.6e-5 rel error vs
// fp32 chain — output threshold is 0.0765).
__global__ __launch_bounds__(256) void gemm_out(
    const unsigned short* __restrict__ A, const float* __restrict__ Bm,
    float* __restrict__ obuf) {
  __shared__ __align__(16) unsigned short Ah[64][40];
  __shared__ __align__(16) unsigned short Bh[64][40];
  __shared__ __align__(16) unsigned short Bl[64][40];
  const int tid = threadIdx.x;
  const int lane = tid & 63;
  const int w = tid >> 6;
  const int row0 = blockIdx.y * 64;
  const int col0 = blockIdx.x * 64;
  const int lrow = tid >> 2;
  const int lk = (tid & 3) << 3;
  const unsigned short* ap = A + (size_t)(row0 + lrow) * KDIM + lk;
  const float* bp = Bm + (size_t)(col0 + lrow) * KDIM + lk;
  const int wr = (w >> 1) << 5;
  const int wc = (w & 1) << 5;
  const int li = lane & 15;
  const int kA = (lane >> 4) << 3;

  f32x4v acc[2][2];
#pragma unroll
  for (int m = 0; m < 2; ++m)
#pragma unroll
    for (int n = 0; n < 2; ++n)
      acc[m][n] = (f32x4v){0.f, 0.f, 0.f, 0.f};

  uint4 ua = *(const uint4*)(ap);
  float4 rb0 = *(const float4*)(bp);
  float4 rb1 = *(const float4*)(bp + 4);
  for (int k0 = 0; k0 < KDIM; k0 += 32) {
    __syncthreads();
    *(uint4*)&Ah[lrow][lk] = ua;
    split8(rb0, rb1, &Bh[lrow][lk], &Bl[lrow][lk]);
    if (k0 + 32 < KDIM) {
      ua = *(const uint4*)(ap + k0 + 32);
      rb0 = *(const float4*)(bp + k0 + 32);
      rb1 = *(const float4*)(bp + k0 + 36);
    }
    __syncthreads();
    bf16x8v ah[2], bh[2], bl[2];
#pragma unroll
    for (int m = 0; m < 2; ++m) {
      ah[m] = *(const bf16x8v*)&Ah[wr + 16 * m + li][kA];
      bh[m] = *(const bf16x8v*)&Bh[wc + 16 * m + li][kA];
      bl[m] = *(const bf16x8v*)&Bl[wc + 16 * m + li][kA];
    }
#pragma unroll
    for (int m = 0; m < 2; ++m)
#pragma unroll
      for (int n = 0; n < 2; ++n) {
        acc[m][n] = __builtin_amdgcn_mfma_f32_16x16x32_bf16(ah[m], bh[n], acc[m][n], 0, 0, 0);
        acc[m][n] = __builtin_amdgcn_mfma_f32_16x16x32_bf16(ah[m], bl[n], acc[m][n], 0, 0, 0);
      }
  }

  const int r4 = (lane >> 4) << 2;
#pragma unroll
  for (int m = 0; m < 2; ++m)
#pragma unroll
    for (int n = 0; n < 2; ++n)
#pragma unroll
      for (int j = 0; j < 4; ++j) {
        const int r = row0 + wr + 16 * m + r4 + j;
        const int c = col0 + wc + 16 * n + li;
        obuf[(size_t)r * DIM_D + c] = acc[m][n][j];
      }
}

extern "C" void kernel_launch(void* const* d_in, const int* in_sizes, int n_in,
                              void* d_out, int out_size, void* d_ws,
                              size_t ws_size, hipStream_t stream) {
  (void)out_size; (void)ws_size;
  const float* x = (const float*)d_in[0];
  const float* wqkv = (const float*)d_in[1];
  const float* wout = (const float*)d_in[2];
  for (int i = 0; i < n_in; ++i) {
    if (in_sizes[i] == NUM_B * SEQ_T * DIM_D) x = (const float*)d_in[i];
    else if (in_sizes[i] == 3 * DIM_D * DIM_D) wqkv = (const float*)d_in[i];
    else if (in_sizes[i] == DIM_D * DIM_D) wout = (const float*)d_in[i];
  }
  float* out = (float*)d_out;

  const size_t qkv_elems = (size_t)NUM_B * NH * SEQ_T * DH;   // 4.19M
  float* qbuf = (float*)d_ws;
  float* kbuf = qbuf + qkv_elems;
  unsigned short* vbuf = (unsigned short*)(kbuf + qkv_elems);
  unsigned short* ctxb = vbuf + qkv_elems;
  unsigned short* kbf = ctxb + (size_t)NUM_B * SEQ_T * DIM_D;  // bf16 K tiles

  gemm_qk<<<dim3(2 * DIM_D / 128, NUM_B * SEQ_T / 64), 512, 0, stream>>>(
      x, wqkv, qbuf, kbuf, kbf);
  gemm_v<<<dim3(DIM_D / 128, NUM_B * SEQ_T / 64), 512, 0, stream>>>(
      x, wqkv + (size_t)2 * DIM_D * KDIM, vbuf);
  attn_topk<<<dim3(NUM_B * NH * (SEQ_T / 128)), 512, 0, stream>>>(
      qbuf, kbuf, kbf, vbuf, ctxb);
  gemm_out<<<dim3(DIM_D / 64, NUM_B * SEQ_T / 64), 256, 0, stream>>>(
      ctxb, wout, out);
}